// Round 3
// baseline (7801.882 us; speedup 1.0000x reference)
//
#include <hip/hip_runtime.h>
#include <math.h>

// Problem constants
constexpr int Bq = 2;
constexpr int Nq = 100000;
constexpr int Mq = 25000;
constexpr int Kq = 16;
// rows (B,M,K) = 800000 ; points B*M = 50000

// ---- workspace layout (bytes) ----
constexpr size_t OFF_NFX = 0;                    // 50000*576*4 = 115,200,000
constexpr size_t OFF_VI  = 115200000;            // 38,400,000 (dead after k_chain)
constexpr size_t OFF_Y8  = 115200000;            // aliases vi (written in k_gemm)
constexpr size_t OFF_DS  = 153600000;            // 784 doubles
constexpr size_t OFF_FS  = OFF_DS + 8192;        // 784 floats
constexpr size_t OFF_WC  = OFF_DS + 16384;       // 576*128*4 = 294912
// total ~153.9 MB ; y9 lives in d_out

// ---- stat-group offsets (shared for ds doubles and fs floats)
constexpr int G_BN1 = 0;    // C=32  n=800000
constexpr int G_BN5 = 64;   // C=8   n=800000
constexpr int G_BN4 = 80;   // C=32  n=200000
constexpr int G_BN2 = 144;  // C=32  n=800000
constexpr int G_BN6 = 208;  // C=8   n=800000
constexpr int G_BN3 = 224;  // C=8   n=800000
constexpr int G_BN7 = 240;  // C=16  n=800000
constexpr int G_BN8 = 272;  // C=128 n=50000
constexpr int G_BN9 = 528;  // C=128 n=50000

// ---- shared-weight LDS layout (union, floats)
constexpr int WL_MLP  = 0;     // 384
constexpr int WL_BMLP = 384;   // 32
constexpr int WL_GU   = 416;   // 1024
constexpr int WL_BGU  = 1440;  // 32
constexpr int WL_GM0  = 1472;  // 256
constexpr int WL_BGM0 = 1728;  // 8
constexpr int WL_GM1  = 1736;  // 32
constexpr int WL_BGM1 = 1768;  // 4
constexpr int WL_WN0  = 1772;  // 96
constexpr int WL_BWN0 = 1868;  // 8
constexpr int WL_WN1  = 1876;  // 64
constexpr int WL_BWN1 = 1940;  // 8
constexpr int WL_WN2  = 1948;  // 128
constexpr int WL_BWN2 = 2076;  // 16
constexpr int WL_U1   = 2092;  // 2048
constexpr int WL_BU1  = 4140;  // 32
constexpr int WL_FS   = 4172;  // 784
constexpr int WL_TOT  = 4956;

struct P {
  const float *dxyz,*sxyz,*dfeat,*dnorm,*snorm;
  const float *w_mlp,*b_mlp,*w_gu,*b_gu,*w_gm0,*b_gm0,*w_gm1,*b_gm1;
  const float *w_u1,*b_u1,*w_wn0,*b_wn0,*w_wn1,*b_wn1,*w_wn2,*b_wn2;
  const float *w_u2,*b_u2,*w_us,*b_us;
  const int* nei;
  float* vi; float* nfx; float* y8; float* y9; double* ds; float* fs;
  float* wc; float* out;
};

__device__ __forceinline__ float lrelu(float x){ return x > 0.f ? x : 0.1f*x; }

#define CPW(off, src, n) for (int i = t; i < (n); i += 256) wl[(off)+i] = (src)[i];

__device__ __forceinline__ void load_vi(const P& p, int row, float v[12]){
  const float4* vp = (const float4*)(p.vi + (size_t)row*12);
  float4 a = vp[0], b = vp[1], c = vp[2];
  v[0]=a.x; v[1]=a.y; v[2]=a.z; v[3]=a.w;
  v[4]=b.x; v[5]=b.y; v[6]=b.z; v[7]=b.w;
  v[8]=c.x; v[9]=c.y; v[10]=c.z; v[11]=c.w;
}
__device__ __forceinline__ void featpe_w(const float* wl, const float v[12], float fp[32]){
  #pragma unroll
  for (int c = 0; c < 32; c++){
    float y = wl[WL_BMLP+c];
    #pragma unroll
    for (int j = 0; j < 12; j++) y += wl[WL_MLP+c*12+j]*v[j];
    fp[c] = fmaxf((y - wl[WL_FS+G_BN1+c])*wl[WL_FS+G_BN1+32+c], 0.f);
  }
}
__device__ __forceinline__ void wchain0_w(const float* wl, const float v[12], float w0[8]){
  #pragma unroll
  for (int c = 0; c < 8; c++){
    float y = wl[WL_BWN0+c];
    #pragma unroll
    for (int j = 0; j < 12; j++) y += wl[WL_WN0+c*12+j]*v[j];
    w0[c] = fmaxf((y - wl[WL_FS+G_BN5+c])*wl[WL_FS+G_BN5+8+c], 0.f);
  }
}

// ---------------------------------------------------------------- k_tr: build wcat[576][128] = [u2^T ; us^T]
__global__ __launch_bounds__(256) void k_tr(P p){
  int i = blockIdx.x*256 + threadIdx.x;       // 288 blocks * 256 = 73728
  if (i < 576*128){
    int d = i >> 7, o = i & 127;
    p.wc[i] = (d < 512) ? p.w_u2[(size_t)o*512 + d] : p.w_us[(size_t)o*64 + (d-512)];
  }
}

// ---------------------------------------------------------------- P1: vi + bn1/bn5 moments (5 rows/thread)
__global__ __launch_bounds__(256) void k_vi(P p){
  __shared__ float wl[520];   // V layout: mlp 0, bmlp 384, wn0 416, bwn0 512
  __shared__ float ls[80];
  int t = threadIdx.x;
  CPW(0,   p.w_mlp, 384)
  CPW(384, p.b_mlp, 32)
  CPW(416, p.w_wn0, 96)
  CPW(512, p.b_wn0, 8)
  if (t < 80) ls[t] = 0.f;
  __syncthreads();

  float a1[32], q1[32], a5[8], q5[8];
  #pragma unroll
  for (int c = 0; c < 32; c++){ a1[c]=0.f; q1[c]=0.f; }
  #pragma unroll
  for (int c = 0; c < 8; c++){ a5[c]=0.f; q5[c]=0.f; }

  int base = blockIdx.x*1280 + t;
  for (int r = 0; r < 5; r++){
    int row = base + r*256;
    int b   = row / (Mq*Kq);
    int rem = row - b*(Mq*Kq);
    int m   = rem >> 4;
    int bm  = b*Mq + m;
    int idx = p.nei[row];

    const float* gx = p.dxyz  + ((size_t)b*Nq + idx)*3;
    const float* gn = p.dnorm + ((size_t)b*Nq + idx)*3;
    const float* sx = p.sxyz  + (size_t)bm*3;
    const float* sn = p.snorm + (size_t)bm*3;

    float lx = gx[0]-sx[0], ly = gx[1]-sx[1], lz = gx[2]-sx[2];
    float gnx = gn[0], gny = gn[1], gnz = gn[2];
    float snx = sn[0], sny = sn[1], snz = sn[2];

    float rn = sqrtf(lx*lx + ly*ly + lz*lz);
    float rd = fmaxf(rn, 1e-12f);
    float rx = lx/rd, ry = ly/rd, rz = lz/rd;
    float proj = snx*rx + sny*ry + snz*rz;
    float vx = snx - proj*rx, vy = sny - proj*ry, vz = snz - proj*rz;
    float vn = sqrtf(vx*vx + vy*vy + vz*vz);
    float vd = fmaxf(vn, 1e-12f);
    vx /= vd; vy /= vd; vz /= vd;
    float wx = ry*vz - rz*vy, wy = rz*vx - rx*vz, wz = rx*vy - ry*vx;
    float wnn = sqrtf(wx*wx + wy*wy + wz*wz);
    float wd = fmaxf(wnn, 1e-12f);
    wx /= wd; wy /= wd; wz /= wd;
    float cx = gny*snz - gnz*sny, cy = gnz*snx - gnx*snz, cz = gnx*sny - gny*snx;

    float v[12];
    v[0] = gnx*snx + gny*sny + gnz*snz;
    v[1] = proj;
    v[2] = rx*gnx + ry*gny + rz*gnz;
    v[3] = lx*snx + ly*sny + lz*snz;
    v[4] = v[2];
    v[5] = gnx*vx + gny*vy + gnz*vz;
    v[6] = gnx*wx + gny*wy + gnz*wz;
    v[7] = lx*cx + ly*cy + lz*cz;
    v[8] = rn;
    v[9] = lx; v[10] = ly; v[11] = lz;

    float4* vo = (float4*)(p.vi + (size_t)row*12);
    vo[0] = make_float4(v[0],v[1],v[2],v[3]);
    vo[1] = make_float4(v[4],v[5],v[6],v[7]);
    vo[2] = make_float4(v[8],v[9],v[10],v[11]);

    #pragma unroll
    for (int c = 0; c < 32; c++){
      float y = wl[384+c];
      #pragma unroll
      for (int j = 0; j < 12; j++) y += wl[c*12 + j]*v[j];
      a1[c] += y; q1[c] += y*y;
    }
    #pragma unroll
    for (int c = 0; c < 8; c++){
      float y = wl[512+c];
      #pragma unroll
      for (int j = 0; j < 12; j++) y += wl[416 + c*12 + j]*v[j];
      a5[c] += y; q5[c] += y*y;
    }
  }
  int lane = t & 63;
  #pragma unroll
  for (int i = 0; i < 32; i++){
    int c = (lane + i) & 31;
    atomicAdd(&ls[c], a1[c]); atomicAdd(&ls[32+c], q1[c]);
  }
  #pragma unroll
  for (int i = 0; i < 8; i++){
    int c = (lane + i) & 7;
    atomicAdd(&ls[64+c], a5[c]); atomicAdd(&ls[72+c], q5[c]);
  }
  __syncthreads();
  if (t < 32){
    atomicAdd(&p.ds[G_BN1+t], (double)ls[t]);
    atomicAdd(&p.ds[G_BN1+32+t], (double)ls[32+t]);
  } else if (t < 40){
    int c = t - 32;
    atomicAdd(&p.ds[G_BN5+c], (double)ls[64+c]);
    atomicAdd(&p.ds[G_BN5+8+c], (double)ls[72+c]);
  }
}

// ---------------------------------------------------------------- P1b: bn4 (u1) moments over B*N (1 row/thread)
__global__ __launch_bounds__(256) void k_u1s(P p){
  __shared__ float wl[2080];   // u1 0..2048, bu1 2048..2080
  __shared__ float ls[64];
  int t = threadIdx.x;
  CPW(0,    p.w_u1, 2048)
  CPW(2048, p.b_u1, 32)
  if (t < 64) ls[t] = 0.f;
  __syncthreads();
  float a4[32], q4[32];
  #pragma unroll
  for (int c = 0; c < 32; c++){ a4[c]=0.f; q4[c]=0.f; }
  int row = blockIdx.x*256 + t;               // 782 blocks
  if (row < Bq*Nq){
    const float4* f4 = (const float4*)(p.dfeat + (size_t)row*64);
    float fr[64];
    #pragma unroll
    for (int q = 0; q < 16; q++){
      float4 x = f4[q];
      fr[q*4+0]=x.x; fr[q*4+1]=x.y; fr[q*4+2]=x.z; fr[q*4+3]=x.w;
    }
    #pragma unroll
    for (int c = 0; c < 32; c++){
      float y = wl[2048+c];
      #pragma unroll
      for (int j = 0; j < 64; j++) y += wl[c*64 + j]*fr[j];
      a4[c] += y; q4[c] += y*y;
    }
  }
  int lane = t & 63;
  #pragma unroll
  for (int i = 0; i < 32; i++){
    int c = (lane + i) & 31;
    atomicAdd(&ls[c], a4[c]); atomicAdd(&ls[32+c], q4[c]);
  }
  __syncthreads();
  if (t < 32){
    atomicAdd(&p.ds[G_BN4+t], (double)ls[t]);
    atomicAdd(&p.ds[G_BN4+32+t], (double)ls[32+t]);
  }
}

// ---------------------------------------------------------------- stat finalize
__device__ __forceinline__ void fin_group(const double* ds, float* fs, int off, int C, double n){
  for (int c = threadIdx.x; c < C; c += blockDim.x){
    double s = ds[off+c], q = ds[off+C+c];
    double mu = s/n;
    double va = q/n - mu*mu;
    if (va < 0.0) va = 0.0;
    fs[off+c]   = (float)mu;
    fs[off+C+c] = 1.f/sqrtf((float)va + 1e-5f);
  }
}
__global__ void k_fin1(P p){ fin_group(p.ds,p.fs,G_BN1,32,800000.0); fin_group(p.ds,p.fs,G_BN5,8,800000.0); fin_group(p.ds,p.fs,G_BN4,32,200000.0); }
__global__ void k_fin2(P p){ fin_group(p.ds,p.fs,G_BN2,32,800000.0); fin_group(p.ds,p.fs,G_BN6,8,800000.0); }
__global__ void k_fin3(P p){ fin_group(p.ds,p.fs,G_BN3,8,800000.0);  fin_group(p.ds,p.fs,G_BN7,16,800000.0); }
__global__ void k_fin4(P p){ fin_group(p.ds,p.fs,G_BN8,128,50000.0); fin_group(p.ds,p.fs,G_BN9,128,50000.0); }

// ---------------------------------------------------------------- P2: bn2/bn6 moments (5 rows/thread)
__global__ __launch_bounds__(256) void k_s2(P p){
  __shared__ float wl[WL_TOT];
  __shared__ float ls[80];
  int t = threadIdx.x;
  CPW(WL_MLP,  p.w_mlp, 384) CPW(WL_BMLP, p.b_mlp, 32)
  CPW(WL_GU,   p.w_gu, 1024) CPW(WL_BGU,  p.b_gu,  32)
  CPW(WL_WN0,  p.w_wn0, 96)  CPW(WL_BWN0, p.b_wn0, 8)
  CPW(WL_WN1,  p.w_wn1, 64)  CPW(WL_BWN1, p.b_wn1, 8)
  CPW(WL_FS,   p.fs, 784)
  if (t < 80) ls[t] = 0.f;
  __syncthreads();
  float a2[32], q2[32], a6[8], q6[8];
  #pragma unroll
  for (int c = 0; c < 32; c++){ a2[c]=0.f; q2[c]=0.f; }
  #pragma unroll
  for (int c = 0; c < 8; c++){ a6[c]=0.f; q6[c]=0.f; }
  int base = blockIdx.x*1280 + t;
  for (int r = 0; r < 5; r++){
    int row = base + r*256;
    float v[12]; load_vi(p, row, v);
    float fp[32]; featpe_w(wl, v, fp);
    #pragma unroll
    for (int c = 0; c < 32; c++){
      float y = wl[WL_BGU+c];
      #pragma unroll
      for (int j = 0; j < 32; j++) y += wl[WL_GU+c*32+j]*fp[j];
      a2[c] += y; q2[c] += y*y;
    }
    float w0[8]; wchain0_w(wl, v, w0);
    #pragma unroll
    for (int c = 0; c < 8; c++){
      float y = wl[WL_BWN1+c];
      #pragma unroll
      for (int j = 0; j < 8; j++) y += wl[WL_WN1+c*8+j]*w0[j];
      a6[c] += y; q6[c] += y*y;
    }
  }
  int lane = t & 63;
  #pragma unroll
  for (int i = 0; i < 32; i++){
    int c = (lane + i) & 31;
    atomicAdd(&ls[c], a2[c]); atomicAdd(&ls[32+c], q2[c]);
  }
  #pragma unroll
  for (int i = 0; i < 8; i++){
    int c = (lane + i) & 7;
    atomicAdd(&ls[64+c], a6[c]); atomicAdd(&ls[72+c], q6[c]);
  }
  __syncthreads();
  if (t < 32){
    atomicAdd(&p.ds[G_BN2+t], (double)ls[t]);
    atomicAdd(&p.ds[G_BN2+32+t], (double)ls[32+t]);
  } else if (t < 40){
    int c = t - 32;
    atomicAdd(&p.ds[G_BN6+c], (double)ls[64+c]);
    atomicAdd(&p.ds[G_BN6+8+c], (double)ls[72+c]);
  }
}

// ---------------------------------------------------------------- P3: bn3/bn7 moments
__global__ __launch_bounds__(256) void k_s3(P p){
  __shared__ float wl[WL_TOT];
  __shared__ float ls[48];
  int t = threadIdx.x;
  CPW(WL_MLP,  p.w_mlp, 384) CPW(WL_BMLP, p.b_mlp, 32)
  CPW(WL_GU,   p.w_gu, 1024) CPW(WL_BGU,  p.b_gu,  32)
  CPW(WL_GM0,  p.w_gm0, 256) CPW(WL_BGM0, p.b_gm0, 8)
  CPW(WL_WN0,  p.w_wn0, 96)  CPW(WL_BWN0, p.b_wn0, 8)
  CPW(WL_WN1,  p.w_wn1, 64)  CPW(WL_BWN1, p.b_wn1, 8)
  CPW(WL_WN2,  p.w_wn2, 128) CPW(WL_BWN2, p.b_wn2, 16)
  CPW(WL_FS,   p.fs, 784)
  if (t < 48) ls[t] = 0.f;
  __syncthreads();
  int lane = t & 63;
  int k  = lane & 15;
  int pl = (t >> 6)*4 + (lane >> 4);
  float a3[8], q3[8], a7[16], q7[16];
  #pragma unroll
  for (int c = 0; c < 8; c++){ a3[c]=0.f; q3[c]=0.f; }
  #pragma unroll
  for (int c = 0; c < 16; c++){ a7[c]=0.f; q7[c]=0.f; }

  for (int it = 0; it < 5; it++){
    int pg = blockIdx.x*80 + it*16 + pl;
    int row = pg*16 + k;
    float v[12]; load_vi(p, row, v);
    float fp[32]; featpe_w(wl, v, fp);
    float g[32];
    #pragma unroll
    for (int c = 0; c < 32; c++){
      float y = wl[WL_BGU+c];
      #pragma unroll
      for (int j = 0; j < 32; j++) y += wl[WL_GU+c*32+j]*fp[j];
      g[c] = (y - wl[WL_FS+G_BN2+c])*wl[WL_FS+G_BN2+32+c];
    }
    #pragma unroll
    for (int c = 0; c < 32; c++){
      float mx = g[c];
      mx = fmaxf(mx, __shfl_xor(mx, 1, 16));
      mx = fmaxf(mx, __shfl_xor(mx, 2, 16));
      mx = fmaxf(mx, __shfl_xor(mx, 4, 16));
      mx = fmaxf(mx, __shfl_xor(mx, 8, 16));
      g[c] -= mx;
    }
    #pragma unroll
    for (int c = 0; c < 8; c++){
      float y = wl[WL_BGM0+c];
      #pragma unroll
      for (int j = 0; j < 32; j++) y += wl[WL_GM0+c*32+j]*g[j];
      a3[c] += y; q3[c] += y*y;
    }
    float w0[8]; wchain0_w(wl, v, w0);
    float w1[8];
    #pragma unroll
    for (int c = 0; c < 8; c++){
      float y = wl[WL_BWN1+c];
      #pragma unroll
      for (int j = 0; j < 8; j++) y += wl[WL_WN1+c*8+j]*w0[j];
      w1[c] = fmaxf((y - wl[WL_FS+G_BN6+c])*wl[WL_FS+G_BN6+8+c], 0.f);
    }
    #pragma unroll
    for (int c = 0; c < 16; c++){
      float y = wl[WL_BWN2+c];
      #pragma unroll
      for (int j = 0; j < 8; j++) y += wl[WL_WN2+c*8+j]*w1[j];
      a7[c] += y; q7[c] += y*y;
    }
  }
  #pragma unroll
  for (int i = 0; i < 8; i++){
    int c = (lane + i) & 7;
    atomicAdd(&ls[c], a3[c]); atomicAdd(&ls[8+c], q3[c]);
  }
  #pragma unroll
  for (int i = 0; i < 16; i++){
    int c = (lane + i) & 15;
    atomicAdd(&ls[16+c], a7[c]); atomicAdd(&ls[32+c], q7[c]);
  }
  __syncthreads();
  if (t < 8){
    atomicAdd(&p.ds[G_BN3+t], (double)ls[t]);
    atomicAdd(&p.ds[G_BN3+8+t], (double)ls[8+t]);
  } else if (t < 24){
    int c = t - 8;
    atomicAdd(&p.ds[G_BN7+c], (double)ls[16+c]);
    atomicAdd(&p.ds[G_BN7+16+c], (double)ls[32+c]);
  }
}

// ---------------------------------------------------------------- P4a: chain → nfx[pt][576] = [nf(512) | smx(64)]
__global__ __launch_bounds__(256) void k_chain(P p){
  __shared__ float wl[WL_TOT];
  __shared__ __align__(16) float sgf[16*640];   // [pt][c*20 + kk]
  __shared__ __align__(16) float swv[16*320];   // [pt][kp*20 + wi]
  int t = threadIdx.x;
  CPW(WL_MLP,  p.w_mlp, 384) CPW(WL_BMLP, p.b_mlp, 32)
  CPW(WL_GU,   p.w_gu, 1024) CPW(WL_BGU,  p.b_gu,  32)
  CPW(WL_GM0,  p.w_gm0, 256) CPW(WL_BGM0, p.b_gm0, 8)
  CPW(WL_GM1,  p.w_gm1, 32)  CPW(WL_BGM1, p.b_gm1, 4)
  CPW(WL_WN0,  p.w_wn0, 96)  CPW(WL_BWN0, p.b_wn0, 8)
  CPW(WL_WN1,  p.w_wn1, 64)  CPW(WL_BWN1, p.b_wn1, 8)
  CPW(WL_WN2,  p.w_wn2, 128) CPW(WL_BWN2, p.b_wn2, 16)
  CPW(WL_U1,   p.w_u1, 2048) CPW(WL_BU1,  p.b_u1, 32)
  CPW(WL_FS,   p.fs, 784)
  __syncthreads();

  int lane = t & 63;
  int k  = lane & 15;
  int pl = (t >> 6)*4 + (lane >> 4);
  int pg = blockIdx.x*16 + pl;
  int b  = pg / Mq;
  int row = pg*16 + k;

  // ---- per-neighbor chain
  float v[12]; load_vi(p, row, v);
  float fp[32]; featpe_w(wl, v, fp);
  float g[32];
  #pragma unroll
  for (int c = 0; c < 32; c++){
    float y = wl[WL_BGU+c];
    #pragma unroll
    for (int j = 0; j < 32; j++) y += wl[WL_GU+c*32+j]*fp[j];
    g[c] = (y - wl[WL_FS+G_BN2+c])*wl[WL_FS+G_BN2+32+c];
  }
  #pragma unroll
  for (int c = 0; c < 32; c++){
    float mx = g[c];
    mx = fmaxf(mx, __shfl_xor(mx, 1, 16));
    mx = fmaxf(mx, __shfl_xor(mx, 2, 16));
    mx = fmaxf(mx, __shfl_xor(mx, 4, 16));
    mx = fmaxf(mx, __shfl_xor(mx, 8, 16));
    g[c] -= mx;
  }
  float sc[8];
  #pragma unroll
  for (int c = 0; c < 8; c++){
    float y = wl[WL_BGM0+c];
    #pragma unroll
    for (int j = 0; j < 32; j++) y += wl[WL_GM0+c*32+j]*g[j];
    sc[c] = fmaxf((y - wl[WL_FS+G_BN3+c])*wl[WL_FS+G_BN3+8+c], 0.f);
  }
  float scr[4];
  #pragma unroll
  for (int h = 0; h < 4; h++){
    float y = wl[WL_BGM1+h];
    #pragma unroll
    for (int j = 0; j < 8; j++) y += wl[WL_GM1+h*8+j]*sc[j];
    scr[h] = 1.f/(1.f + expf(-y));
  }
  float w0[8]; wchain0_w(wl, v, w0);
  float w1[8];
  #pragma unroll
  for (int c = 0; c < 8; c++){
    float y = wl[WL_BWN1+c];
    #pragma unroll
    for (int j = 0; j < 8; j++) y += wl[WL_WN1+c*8+j]*w0[j];
    w1[c] = fmaxf((y - wl[WL_FS+G_BN6+c])*wl[WL_FS+G_BN6+8+c], 0.f);
  }
  {
    float wv[16];
    #pragma unroll
    for (int c = 0; c < 16; c++){
      float y = wl[WL_BWN2+c];
      #pragma unroll
      for (int j = 0; j < 8; j++) y += wl[WL_WN2+c*8+j]*w1[j];
      wv[c] = fmaxf((y - wl[WL_FS+G_BN7+c])*wl[WL_FS+G_BN7+16+c], 0.f);
    }
    float4* d4p = (float4*)&swv[(pl*16 + k)*20];
    d4p[0] = make_float4(wv[0],wv[1],wv[2],wv[3]);
    d4p[1] = make_float4(wv[4],wv[5],wv[6],wv[7]);
    d4p[2] = make_float4(wv[8],wv[9],wv[10],wv[11]);
    d4p[3] = make_float4(wv[12],wv[13],wv[14],wv[15]);
  }

  // ---- dense_feats gather + u1 + bn4 + leaky + score → sgf[c][k]
  int idx = p.nei[row];
  const float4* f4 = (const float4*)(p.dfeat + ((size_t)b*Nq + idx)*64);
  float fr[64];
  #pragma unroll
  for (int q = 0; q < 16; q++){
    float4 x = f4[q];
    fr[q*4+0]=x.x; fr[q*4+1]=x.y; fr[q*4+2]=x.z; fr[q*4+3]=x.w;
  }
  #pragma unroll
  for (int c = 0; c < 32; c++){
    float y = wl[WL_BU1+c];
    #pragma unroll
    for (int j = 0; j < 64; j++) y += wl[WL_U1+c*64+j]*fr[j];
    float fx = lrelu((y - wl[WL_FS+G_BN4+c])*wl[WL_FS+G_BN4+32+c]);
    sgf[pl*640 + c*20 + k] = fx*scr[c >> 3];
  }
  // ---- max over K of dense_feats; lane keeps quad q==k
  float sx0=0.f, sx1=0.f, sx2=0.f, sx3=0.f;
  #pragma unroll
  for (int q = 0; q < 16; q++){
    float m0=fr[q*4+0], m1=fr[q*4+1], m2=fr[q*4+2], m3=fr[q*4+3];
    m0=fmaxf(m0,__shfl_xor(m0,1,16)); m0=fmaxf(m0,__shfl_xor(m0,2,16)); m0=fmaxf(m0,__shfl_xor(m0,4,16)); m0=fmaxf(m0,__shfl_xor(m0,8,16));
    m1=fmaxf(m1,__shfl_xor(m1,1,16)); m1=fmaxf(m1,__shfl_xor(m1,2,16)); m1=fmaxf(m1,__shfl_xor(m1,4,16)); m1=fmaxf(m1,__shfl_xor(m1,8,16));
    m2=fmaxf(m2,__shfl_xor(m2,1,16)); m2=fmaxf(m2,__shfl_xor(m2,2,16)); m2=fmaxf(m2,__shfl_xor(m2,4,16)); m2=fmaxf(m2,__shfl_xor(m2,8,16));
    m3=fmaxf(m3,__shfl_xor(m3,1,16)); m3=fmaxf(m3,__shfl_xor(m3,2,16)); m3=fmaxf(m3,__shfl_xor(m3,4,16)); m3=fmaxf(m3,__shfl_xor(m3,8,16));
    if (q == k){ sx0=m0; sx1=m1; sx2=m2; sx3=m3; }
  }
  __syncthreads();   // sgf + swv visible

  // ---- einsum: lane accumulates nf[c=k][*] and nf[c=k+16][*]
  float ga[16], gb[16];
  {
    const float4* ra = (const float4*)&sgf[pl*640 + k*20];
    const float4* rb = (const float4*)&sgf[pl*640 + (k+16)*20];
    float4 t0=ra[0], t1=ra[1], t2=ra[2], t3=ra[3];
    ga[0]=t0.x; ga[1]=t0.y; ga[2]=t0.z; ga[3]=t0.w;
    ga[4]=t1.x; ga[5]=t1.y; ga[6]=t1.z; ga[7]=t1.w;
    ga[8]=t2.x; ga[9]=t2.y; ga[10]=t2.z; ga[11]=t2.w;
    ga[12]=t3.x; ga[13]=t3.y; ga[14]=t3.z; ga[15]=t3.w;
    t0=rb[0]; t1=rb[1]; t2=rb[2]; t3=rb[3];
    gb[0]=t0.x; gb[1]=t0.y; gb[2]=t0.z; gb[3]=t0.w;
    gb[4]=t1.x; gb[5]=t1.y; gb[6]=t1.z; gb[7]=t1.w;
    gb[8]=t2.x; gb[9]=t2.y; gb[10]=t2.z; gb[11]=t2.w;
    gb[12]=t3.x; gb[13]=t3.y; gb[14]=t3.z; gb[15]=t3.w;
  }
  float nf0[16], nf1[16];
  #pragma unroll
  for (int wi = 0; wi < 16; wi++){ nf0[wi]=0.f; nf1[wi]=0.f; }
  #pragma unroll 4
  for (int kp = 0; kp < 16; kp++){
    const float4* wp = (const float4*)&swv[(pl*16 + kp)*20];
    float4 wa = wp[0], wb = wp[1], wc = wp[2], wd = wp[3];
    float wvv[16] = {wa.x,wa.y,wa.z,wa.w, wb.x,wb.y,wb.z,wb.w,
                     wc.x,wc.y,wc.z,wc.w, wd.x,wd.y,wd.z,wd.w};
    #pragma unroll
    for (int wi = 0; wi < 16; wi++){
      nf0[wi] += ga[kp]*wvv[wi];
      nf1[wi] += gb[kp]*wvv[wi];
    }
  }
  float* nrow = p.nfx + (size_t)pg*576;
  {
    float4* na = (float4*)(nrow + k*16);
    na[0] = make_float4(nf0[0],nf0[1],nf0[2],nf0[3]);
    na[1] = make_float4(nf0[4],nf0[5],nf0[6],nf0[7]);
    na[2] = make_float4(nf0[8],nf0[9],nf0[10],nf0[11]);
    na[3] = make_float4(nf0[12],nf0[13],nf0[14],nf0[15]);
    float4* nb = (float4*)(nrow + (k+16)*16);
    nb[0] = make_float4(nf1[0],nf1[1],nf1[2],nf1[3]);
    nb[1] = make_float4(nf1[4],nf1[5],nf1[6],nf1[7]);
    nb[2] = make_float4(nf1[8],nf1[9],nf1[10],nf1[11]);
    nb[3] = make_float4(nf1[12],nf1[13],nf1[14],nf1[15]);
    *(float4*)(nrow + 512 + k*4) = make_float4(sx0,sx1,sx2,sx3);
  }
}

// ---------------------------------------------------------------- P4b: GEMM y8|y9 = nfx @ wcat + bn8/bn9 moments
__global__ __launch_bounds__(256) void k_gemm(P p){
  __shared__ __align__(16) float sa[2][512];   // A chunk [pt][32]
  __shared__ float ls[512];
  int t = threadIdx.x;
  ls[t] = 0.f; ls[t+256] = 0.f;
  int o = t & 127, ptg = t >> 7;
  int pg0 = blockIdx.x*16;

  #define STAGE_A(kcx, bufx) { \
    int w0_ = t, w1_ = t + 256; \
    sa[bufx][w0_] = p.nfx[(size_t)(pg0 + (w0_>>5))*576 + (kcx)*32 + (w0_&31)]; \
    sa[bufx][w1_] = p.nfx[(size_t)(pg0 + (w1_>>5))*576 + (kcx)*32 + (w1_&31)]; }

  STAGE_A(0, 0)
  __syncthreads();

  float acc[8], y8r[8];
  #pragma unroll
  for (int i = 0; i < 8; i++){ acc[i]=0.f; y8r[i]=0.f; }

  for (int kc = 0; kc < 18; kc++){
    int cur = kc & 1;
    if (kc < 17) STAGE_A(kc+1, cur^1)
    const float* A = &sa[cur][ptg*256];
    #pragma unroll
    for (int d4 = 0; d4 < 8; d4++){
      const float* wr = p.wc + (size_t)(kc*32 + d4*4)*128 + o;
      float wa = wr[0], wb = wr[128], wcv = wr[256], wd = wr[384];
      #pragma unroll
      for (int i = 0; i < 8; i++){
        float4 av = *(const float4*)&A[i*32 + d4*4];
        acc[i] += av.x*wa + av.y*wb + av.z*wcv + av.w*wd;
      }
    }
    if (kc == 15){
      #pragma unroll
      for (int i = 0; i < 8; i++){ y8r[i] = acc[i]; acc[i] = 0.f; }
    }
    __syncthreads();
  }

  float bu2 = p.b_u2[o], bus = p.b_us[o];
  size_t obase = (size_t)pg0*128 + o;
  float s8=0.f, q8=0.f, s9=0.f, q9=0.f;
  #pragma unroll
  for (int i = 0; i < 8; i++){
    int pt = ptg*8 + i;
    float y8v = y8r[i] + bu2;
    float y9v = acc[i] + bus;
    p.y8[obase + (size_t)pt*128] = y8v;
    p.y9[obase + (size_t)pt*128] = y9v;
    s8 += y8v; q8 += y8v*y8v;
    s9 += y9v; q9 += y9v*y9v;
  }
  atomicAdd(&ls[o], s8);      atomicAdd(&ls[128+o], q8);
  atomicAdd(&ls[256+o], s9);  atomicAdd(&ls[384+o], q9);
  __syncthreads();
  atomicAdd(&p.ds[G_BN8+t], (double)ls[t]);
  atomicAdd(&p.ds[G_BN9+t], (double)ls[256+t]);
}

// ---------------------------------------------------------------- P5: out = leaky(bn8(y8)+bn9(y9))
__global__ __launch_bounds__(256) void k_out(P p){
  size_t i = ((size_t)blockIdx.x*256 + threadIdx.x)*4;
  int c = (int)(i & 127);
  float4 a  = *(const float4*)(p.y8 + i);
  float4 b4 = *(const float4*)(p.y9 + i);
  const float* m8 = p.fs + G_BN8;  const float* i8 = p.fs + G_BN8 + 128;
  const float* m9 = p.fs + G_BN9;  const float* i9 = p.fs + G_BN9 + 128;
  float r0 = lrelu((a.x - m8[c  ])*i8[c  ] + (b4.x - m9[c  ])*i9[c  ]);
  float r1 = lrelu((a.y - m8[c+1])*i8[c+1] + (b4.y - m9[c+1])*i9[c+1]);
  float r2 = lrelu((a.z - m8[c+2])*i8[c+2] + (b4.z - m9[c+2])*i9[c+2]);
  float r3 = lrelu((a.w - m8[c+3])*i8[c+3] + (b4.w - m9[c+3])*i9[c+3]);
  *(float4*)(p.out + i) = make_float4(r0,r1,r2,r3);
}

extern "C" void kernel_launch(void* const* d_in, const int* in_sizes, int n_in,
                              void* d_out, int out_size, void* d_ws, size_t ws_size,
                              hipStream_t stream){
  (void)in_sizes; (void)n_in; (void)out_size; (void)ws_size;
  P p;
  p.dxyz  = (const float*)d_in[0];
  p.sxyz  = (const float*)d_in[1];
  p.dfeat = (const float*)d_in[2];
  p.dnorm = (const float*)d_in[3];
  p.snorm = (const float*)d_in[4];
  p.w_mlp = (const float*)d_in[5];  p.b_mlp = (const float*)d_in[6];
  p.w_gu  = (const float*)d_in[7];  p.b_gu  = (const float*)d_in[8];
  p.w_gm0 = (const float*)d_in[9];  p.b_gm0 = (const float*)d_in[10];
  p.w_gm1 = (const float*)d_in[11]; p.b_gm1 = (const float*)d_in[12];
  p.w_u1  = (const float*)d_in[13]; p.b_u1  = (const float*)d_in[14];
  p.w_wn0 = (const float*)d_in[15]; p.b_wn0 = (const float*)d_in[16];
  p.w_wn1 = (const float*)d_in[17]; p.b_wn1 = (const float*)d_in[18];
  p.w_wn2 = (const float*)d_in[19]; p.b_wn2 = (const float*)d_in[20];
  p.w_u2  = (const float*)d_in[21]; p.b_u2  = (const float*)d_in[22];
  p.w_us  = (const float*)d_in[23]; p.b_us  = (const float*)d_in[24];
  p.nei   = (const int*)d_in[25];
  char* ws = (char*)d_ws;
  p.nfx = (float*)(ws + OFF_NFX);
  p.vi  = (float*)(ws + OFF_VI);
  p.y8  = (float*)(ws + OFF_Y8);
  p.y9  = (float*)d_out;            // y9 lives in d_out; k_out reads then overwrites
  p.ds  = (double*)(ws + OFF_DS);
  p.fs  = (float*)(ws + OFF_FS);
  p.wc  = (float*)(ws + OFF_WC);
  p.out = (float*)d_out;

  hipMemsetAsync(ws + OFF_DS, 0, 784*sizeof(double), stream);

  k_tr   <<< 288, 256, 0, stream>>>(p);
  k_vi   <<< 625, 256, 0, stream>>>(p);
  k_u1s  <<< 782, 256, 0, stream>>>(p);
  k_fin1 <<<   1, 128, 0, stream>>>(p);
  k_s2   <<< 625, 256, 0, stream>>>(p);
  k_fin2 <<<   1, 128, 0, stream>>>(p);
  k_s3   <<< 625, 256, 0, stream>>>(p);
  k_fin3 <<<   1, 128, 0, stream>>>(p);
  k_chain<<<3125, 256, 0, stream>>>(p);
  k_gemm <<<3125, 256, 0, stream>>>(p);
  k_fin4 <<<   1, 128, 0, stream>>>(p);
  k_out  <<<6250, 256, 0, stream>>>(p);
}

// Round 4
// 1394.057 us; speedup vs baseline: 5.5965x; 5.5965x over previous
//
#include <hip/hip_runtime.h>
#include <math.h>

// Problem constants
constexpr int Bq = 2;
constexpr int Nq = 100000;
constexpr int Mq = 25000;
constexpr int Kq = 16;
// rows (B,M,K) = 800000 ; points B*M = 50000

// ---- workspace layout (bytes) ----
constexpr size_t OFF_Y8  = 0;                    // 50000*128*4 = 25,600,000
constexpr size_t OFF_VI  = 25600000;             // 800000*12*4 = 38,400,000
constexpr size_t OFF_DS  = 64000000;             // 784 doubles
constexpr size_t OFF_FS  = OFF_DS + 8192;        // 784 floats
constexpr size_t OFF_WC  = OFF_DS + 16384;       // 576*128*4 = 294912
// total ~64.3 MB ; y9 lives in d_out

// ---- stat-group offsets (shared for ds doubles and fs floats)
constexpr int G_BN1 = 0;    // C=32  n=800000
constexpr int G_BN5 = 64;   // C=8   n=800000
constexpr int G_BN4 = 80;   // C=32  n=200000
constexpr int G_BN2 = 144;  // C=32  n=800000
constexpr int G_BN6 = 208;  // C=8   n=800000
constexpr int G_BN3 = 224;  // C=8   n=800000
constexpr int G_BN7 = 240;  // C=16  n=800000
constexpr int G_BN8 = 272;  // C=128 n=50000
constexpr int G_BN9 = 528;  // C=128 n=50000

struct P {
  const float *dxyz,*sxyz,*dfeat,*dnorm,*snorm;
  const float *w_mlp,*b_mlp,*w_gu,*b_gu,*w_gm0,*b_gm0,*w_gm1,*b_gm1;
  const float *w_u1,*b_u1,*w_wn0,*b_wn0,*w_wn1,*b_wn1,*w_wn2,*b_wn2;
  const float *w_u2,*b_u2,*w_us,*b_us;
  const int* nei;
  float* vi; float* y8; float* y9; double* ds; float* fs;
  float* wc; float* out;
};

__device__ __forceinline__ float lrelu(float x){ return x > 0.f ? x : 0.1f*x; }

__device__ __forceinline__ void load_vi(const P& p, int row, float v[12]){
  const float4* vp = (const float4*)(p.vi + (size_t)row*12);
  float4 a = vp[0], b = vp[1], c = vp[2];
  v[0]=a.x; v[1]=a.y; v[2]=a.z; v[3]=a.w;
  v[4]=b.x; v[5]=b.y; v[6]=b.z; v[7]=b.w;
  v[8]=c.x; v[9]=c.y; v[10]=c.z; v[11]=c.w;
}
// weights read from GLOBAL (uniform constant-offset -> SGPR s_loads, no VGPR pressure)
__device__ __forceinline__ void featpe(const P& p, const float v[12], float fp[32]){
  #pragma unroll
  for (int c = 0; c < 32; c++){
    float y = p.b_mlp[c];
    #pragma unroll
    for (int j = 0; j < 12; j++) y += p.w_mlp[c*12+j]*v[j];
    fp[c] = fmaxf((y - p.fs[G_BN1+c])*p.fs[G_BN1+32+c], 0.f);
  }
}
__device__ __forceinline__ void wchain0(const P& p, const float v[12], float w0[8]){
  #pragma unroll
  for (int c = 0; c < 8; c++){
    float y = p.b_wn0[c];
    #pragma unroll
    for (int j = 0; j < 12; j++) y += p.w_wn0[c*12+j]*v[j];
    w0[c] = fmaxf((y - p.fs[G_BN5+c])*p.fs[G_BN5+8+c], 0.f);
  }
}

// ---------------------------------------------------------------- k_tr: build wcat[576][128] = [u2^T ; us^T]
__global__ __launch_bounds__(256) void k_tr(P p){
  int i = blockIdx.x*256 + threadIdx.x;       // 288 blocks
  if (i < 576*128){
    int d = i >> 7, o = i & 127;
    p.wc[i] = (d < 512) ? p.w_u2[(size_t)o*512 + d] : p.w_us[(size_t)o*64 + (d-512)];
  }
}

// ---------------------------------------------------------------- P1: vi + bn1/bn5 moments (5 rows/thread)
__global__ __launch_bounds__(256) void k_vi(P p){
  __shared__ float ls[80];
  int t = threadIdx.x;
  if (t < 80) ls[t] = 0.f;
  __syncthreads();

  float a1[32], q1[32], a5[8], q5[8];
  #pragma unroll
  for (int c = 0; c < 32; c++){ a1[c]=0.f; q1[c]=0.f; }
  #pragma unroll
  for (int c = 0; c < 8; c++){ a5[c]=0.f; q5[c]=0.f; }

  int base = blockIdx.x*1280 + t;
  for (int r = 0; r < 5; r++){
    int row = base + r*256;
    int b   = row / (Mq*Kq);
    int rem = row - b*(Mq*Kq);
    int m   = rem >> 4;
    int bm  = b*Mq + m;
    int idx = p.nei[row];

    const float* gx = p.dxyz  + ((size_t)b*Nq + idx)*3;
    const float* gn = p.dnorm + ((size_t)b*Nq + idx)*3;
    const float* sx = p.sxyz  + (size_t)bm*3;
    const float* sn = p.snorm + (size_t)bm*3;

    float lx = gx[0]-sx[0], ly = gx[1]-sx[1], lz = gx[2]-sx[2];
    float gnx = gn[0], gny = gn[1], gnz = gn[2];
    float snx = sn[0], sny = sn[1], snz = sn[2];

    float rn = sqrtf(lx*lx + ly*ly + lz*lz);
    float rd = fmaxf(rn, 1e-12f);
    float rx = lx/rd, ry = ly/rd, rz = lz/rd;
    float proj = snx*rx + sny*ry + snz*rz;
    float vx = snx - proj*rx, vy = sny - proj*ry, vz = snz - proj*rz;
    float vn = sqrtf(vx*vx + vy*vy + vz*vz);
    float vd = fmaxf(vn, 1e-12f);
    vx /= vd; vy /= vd; vz /= vd;
    float wx = ry*vz - rz*vy, wy = rz*vx - rx*vz, wz = rx*vy - ry*vx;
    float wnn = sqrtf(wx*wx + wy*wy + wz*wz);
    float wd = fmaxf(wnn, 1e-12f);
    wx /= wd; wy /= wd; wz /= wd;
    float cx = gny*snz - gnz*sny, cy = gnz*snx - gnx*snz, cz = gnx*sny - gny*snx;

    float v[12];
    v[0] = gnx*snx + gny*sny + gnz*snz;
    v[1] = proj;
    v[2] = rx*gnx + ry*gny + rz*gnz;
    v[3] = lx*snx + ly*sny + lz*snz;
    v[4] = v[2];
    v[5] = gnx*vx + gny*vy + gnz*vz;
    v[6] = gnx*wx + gny*wy + gnz*wz;
    v[7] = lx*cx + ly*cy + lz*cz;
    v[8] = rn;
    v[9] = lx; v[10] = ly; v[11] = lz;

    float4* vo = (float4*)(p.vi + (size_t)row*12);
    vo[0] = make_float4(v[0],v[1],v[2],v[3]);
    vo[1] = make_float4(v[4],v[5],v[6],v[7]);
    vo[2] = make_float4(v[8],v[9],v[10],v[11]);

    #pragma unroll
    for (int c = 0; c < 32; c++){
      float y = p.b_mlp[c];
      #pragma unroll
      for (int j = 0; j < 12; j++) y += p.w_mlp[c*12 + j]*v[j];
      a1[c] += y; q1[c] += y*y;
    }
    #pragma unroll
    for (int c = 0; c < 8; c++){
      float y = p.b_wn0[c];
      #pragma unroll
      for (int j = 0; j < 12; j++) y += p.w_wn0[c*12 + j]*v[j];
      a5[c] += y; q5[c] += y*y;
    }
  }
  int lane = t & 63;
  #pragma unroll
  for (int i = 0; i < 32; i++){
    int c = (lane + i) & 31;
    atomicAdd(&ls[c], a1[c]); atomicAdd(&ls[32+c], q1[c]);
  }
  #pragma unroll
  for (int i = 0; i < 8; i++){
    int c = (lane + i) & 7;
    atomicAdd(&ls[64+c], a5[c]); atomicAdd(&ls[72+c], q5[c]);
  }
  __syncthreads();
  if (t < 32){
    atomicAdd(&p.ds[G_BN1+t], (double)ls[t]);
    atomicAdd(&p.ds[G_BN1+32+t], (double)ls[32+t]);
  } else if (t < 40){
    int c = t - 32;
    atomicAdd(&p.ds[G_BN5+c], (double)ls[64+c]);
    atomicAdd(&p.ds[G_BN5+8+c], (double)ls[72+c]);
  }
}

// ---------------------------------------------------------------- P1b: bn4 (u1) moments over B*N (5 rows/thread)
__global__ __launch_bounds__(256) void k_u1s(P p){
  __shared__ float ls[64];
  int t = threadIdx.x;
  if (t < 64) ls[t] = 0.f;
  __syncthreads();
  float a4[32], q4[32];
  #pragma unroll
  for (int c = 0; c < 32; c++){ a4[c]=0.f; q4[c]=0.f; }
  int base = blockIdx.x*1280 + t;             // 157 blocks, guarded
  for (int r = 0; r < 5; r++){
    int row = base + r*256;
    if (row < Bq*Nq){
      const float4* f4 = (const float4*)(p.dfeat + (size_t)row*64);
      float fr[64];
      #pragma unroll
      for (int q = 0; q < 16; q++){
        float4 x = f4[q];
        fr[q*4+0]=x.x; fr[q*4+1]=x.y; fr[q*4+2]=x.z; fr[q*4+3]=x.w;
      }
      #pragma unroll
      for (int c = 0; c < 32; c++){
        float y = p.b_u1[c];
        #pragma unroll
        for (int j = 0; j < 64; j++) y += p.w_u1[c*64 + j]*fr[j];
        a4[c] += y; q4[c] += y*y;
      }
    }
  }
  int lane = t & 63;
  #pragma unroll
  for (int i = 0; i < 32; i++){
    int c = (lane + i) & 31;
    atomicAdd(&ls[c], a4[c]); atomicAdd(&ls[32+c], q4[c]);
  }
  __syncthreads();
  if (t < 32){
    atomicAdd(&p.ds[G_BN4+t], (double)ls[t]);
    atomicAdd(&p.ds[G_BN4+32+t], (double)ls[32+t]);
  }
}

// ---------------------------------------------------------------- stat finalize
__device__ __forceinline__ void fin_group(const double* ds, float* fs, int off, int C, double n){
  for (int c = threadIdx.x; c < C; c += blockDim.x){
    double s = ds[off+c], q = ds[off+C+c];
    double mu = s/n;
    double va = q/n - mu*mu;
    if (va < 0.0) va = 0.0;
    fs[off+c]   = (float)mu;
    fs[off+C+c] = 1.f/sqrtf((float)va + 1e-5f);
  }
}
__global__ void k_fin1(P p){ fin_group(p.ds,p.fs,G_BN1,32,800000.0); fin_group(p.ds,p.fs,G_BN5,8,800000.0); fin_group(p.ds,p.fs,G_BN4,32,200000.0); }
__global__ void k_fin2(P p){ fin_group(p.ds,p.fs,G_BN2,32,800000.0); fin_group(p.ds,p.fs,G_BN6,8,800000.0); }
__global__ void k_fin3(P p){ fin_group(p.ds,p.fs,G_BN3,8,800000.0);  fin_group(p.ds,p.fs,G_BN7,16,800000.0); }
__global__ void k_fin4(P p){ fin_group(p.ds,p.fs,G_BN8,128,50000.0); fin_group(p.ds,p.fs,G_BN9,128,50000.0); }

// ---------------------------------------------------------------- P2: bn2/bn6 moments (5 rows/thread)
__global__ __launch_bounds__(256) void k_s2(P p){
  __shared__ float ls[80];
  int t = threadIdx.x;
  if (t < 80) ls[t] = 0.f;
  __syncthreads();
  float a2[32], q2[32], a6[8], q6[8];
  #pragma unroll
  for (int c = 0; c < 32; c++){ a2[c]=0.f; q2[c]=0.f; }
  #pragma unroll
  for (int c = 0; c < 8; c++){ a6[c]=0.f; q6[c]=0.f; }
  int base = blockIdx.x*1280 + t;
  for (int r = 0; r < 5; r++){
    int row = base + r*256;
    float v[12]; load_vi(p, row, v);
    float fp[32]; featpe(p, v, fp);
    #pragma unroll
    for (int c = 0; c < 32; c++){
      float y = p.b_gu[c];
      #pragma unroll
      for (int j = 0; j < 32; j++) y += p.w_gu[c*32+j]*fp[j];
      a2[c] += y; q2[c] += y*y;
    }
    float w0[8]; wchain0(p, v, w0);
    #pragma unroll
    for (int c = 0; c < 8; c++){
      float y = p.b_wn1[c];
      #pragma unroll
      for (int j = 0; j < 8; j++) y += p.w_wn1[c*8+j]*w0[j];
      a6[c] += y; q6[c] += y*y;
    }
  }
  int lane = t & 63;
  #pragma unroll
  for (int i = 0; i < 32; i++){
    int c = (lane + i) & 31;
    atomicAdd(&ls[c], a2[c]); atomicAdd(&ls[32+c], q2[c]);
  }
  #pragma unroll
  for (int i = 0; i < 8; i++){
    int c = (lane + i) & 7;
    atomicAdd(&ls[64+c], a6[c]); atomicAdd(&ls[72+c], q6[c]);
  }
  __syncthreads();
  if (t < 32){
    atomicAdd(&p.ds[G_BN2+t], (double)ls[t]);
    atomicAdd(&p.ds[G_BN2+32+t], (double)ls[32+t]);
  } else if (t < 40){
    int c = t - 32;
    atomicAdd(&p.ds[G_BN6+c], (double)ls[64+c]);
    atomicAdd(&p.ds[G_BN6+8+c], (double)ls[72+c]);
  }
}

// ---------------------------------------------------------------- P3: bn3/bn7 moments
__global__ __launch_bounds__(256) void k_s3(P p){
  __shared__ float ls[48];
  int t = threadIdx.x;
  if (t < 48) ls[t] = 0.f;
  __syncthreads();
  int lane = t & 63;
  int k  = lane & 15;
  int pl = (t >> 6)*4 + (lane >> 4);
  float a3[8], q3[8], a7[16], q7[16];
  #pragma unroll
  for (int c = 0; c < 8; c++){ a3[c]=0.f; q3[c]=0.f; }
  #pragma unroll
  for (int c = 0; c < 16; c++){ a7[c]=0.f; q7[c]=0.f; }

  for (int it = 0; it < 5; it++){
    int pg = blockIdx.x*80 + it*16 + pl;
    int row = pg*16 + k;
    float v[12]; load_vi(p, row, v);
    float fp[32]; featpe(p, v, fp);
    float g[32];
    #pragma unroll
    for (int c = 0; c < 32; c++){
      float y = p.b_gu[c];
      #pragma unroll
      for (int j = 0; j < 32; j++) y += p.w_gu[c*32+j]*fp[j];
      g[c] = (y - p.fs[G_BN2+c])*p.fs[G_BN2+32+c];
    }
    #pragma unroll
    for (int c = 0; c < 32; c++){
      float mx = g[c];
      mx = fmaxf(mx, __shfl_xor(mx, 1, 16));
      mx = fmaxf(mx, __shfl_xor(mx, 2, 16));
      mx = fmaxf(mx, __shfl_xor(mx, 4, 16));
      mx = fmaxf(mx, __shfl_xor(mx, 8, 16));
      g[c] -= mx;
    }
    #pragma unroll
    for (int c = 0; c < 8; c++){
      float y = p.b_gm0[c];
      #pragma unroll
      for (int j = 0; j < 32; j++) y += p.w_gm0[c*32+j]*g[j];
      a3[c] += y; q3[c] += y*y;
    }
    float w0[8]; wchain0(p, v, w0);
    float w1[8];
    #pragma unroll
    for (int c = 0; c < 8; c++){
      float y = p.b_wn1[c];
      #pragma unroll
      for (int j = 0; j < 8; j++) y += p.w_wn1[c*8+j]*w0[j];
      w1[c] = fmaxf((y - p.fs[G_BN6+c])*p.fs[G_BN6+8+c], 0.f);
    }
    #pragma unroll
    for (int c = 0; c < 16; c++){
      float y = p.b_wn2[c];
      #pragma unroll
      for (int j = 0; j < 8; j++) y += p.w_wn2[c*8+j]*w1[j];
      a7[c] += y; q7[c] += y*y;
    }
  }
  #pragma unroll
  for (int i = 0; i < 8; i++){
    int c = (lane + i) & 7;
    atomicAdd(&ls[c], a3[c]); atomicAdd(&ls[8+c], q3[c]);
  }
  #pragma unroll
  for (int i = 0; i < 16; i++){
    int c = (lane + i) & 15;
    atomicAdd(&ls[16+c], a7[c]); atomicAdd(&ls[32+c], q7[c]);
  }
  __syncthreads();
  if (t < 8){
    atomicAdd(&p.ds[G_BN3+t], (double)ls[t]);
    atomicAdd(&p.ds[G_BN3+8+t], (double)ls[8+t]);
  } else if (t < 24){
    int c = t - 8;
    atomicAdd(&p.ds[G_BN7+c], (double)ls[16+c]);
    atomicAdd(&p.ds[G_BN7+16+c], (double)ls[32+c]);
  }
}

// ---------------------------------------------------------------- P4: fused chain + einsum + 576x128 matvec
// LDS: one 16x592 buffer reused across phases (gf -> wv -> nf|smx), ~40KB -> 4 blocks/CU
__global__ __launch_bounds__(256) void k_chain2(P p){
  __shared__ __align__(16) float sb[16*592];
  __shared__ float ls[512];
  int t = threadIdx.x;
  ls[t] = 0.f; ls[t+256] = 0.f;

  int lane = t & 63;
  int k  = lane & 15;
  int pl = (t >> 6)*4 + (lane >> 4);
  int pg = blockIdx.x*16 + pl;
  int b  = pg / Mq;
  int row = pg*16 + k;
  float* sp = &sb[pl*592];

  // ---- per-neighbor chain (weights via uniform global/SGPR loads)
  float v[12]; load_vi(p, row, v);
  float fp[32]; featpe(p, v, fp);
  float g[32];
  #pragma unroll
  for (int c = 0; c < 32; c++){
    float y = p.b_gu[c];
    #pragma unroll
    for (int j = 0; j < 32; j++) y += p.w_gu[c*32+j]*fp[j];
    g[c] = (y - p.fs[G_BN2+c])*p.fs[G_BN2+32+c];
  }
  #pragma unroll
  for (int c = 0; c < 32; c++){
    float mx = g[c];
    mx = fmaxf(mx, __shfl_xor(mx, 1, 16));
    mx = fmaxf(mx, __shfl_xor(mx, 2, 16));
    mx = fmaxf(mx, __shfl_xor(mx, 4, 16));
    mx = fmaxf(mx, __shfl_xor(mx, 8, 16));
    g[c] -= mx;
  }
  float sc[8];
  #pragma unroll
  for (int c = 0; c < 8; c++){
    float y = p.b_gm0[c];
    #pragma unroll
    for (int j = 0; j < 32; j++) y += p.w_gm0[c*32+j]*g[j];
    sc[c] = fmaxf((y - p.fs[G_BN3+c])*p.fs[G_BN3+8+c], 0.f);
  }
  float scr[4];
  #pragma unroll
  for (int h = 0; h < 4; h++){
    float y = p.b_gm1[h];
    #pragma unroll
    for (int j = 0; j < 8; j++) y += p.w_gm1[h*8+j]*sc[j];
    scr[h] = 1.f/(1.f + expf(-y));
  }
  float w0[8]; wchain0(p, v, w0);
  float w1[8];
  #pragma unroll
  for (int c = 0; c < 8; c++){
    float y = p.b_wn1[c];
    #pragma unroll
    for (int j = 0; j < 8; j++) y += p.w_wn1[c*8+j]*w0[j];
    w1[c] = fmaxf((y - p.fs[G_BN6+c])*p.fs[G_BN6+8+c], 0.f);
  }
  float wv[16];
  #pragma unroll
  for (int c = 0; c < 16; c++){
    float y = p.b_wn2[c];
    #pragma unroll
    for (int j = 0; j < 8; j++) y += p.w_wn2[c*8+j]*w1[j];
    wv[c] = fmaxf((y - p.fs[G_BN7+c])*p.fs[G_BN7+16+c], 0.f);
  }

  // ---- gather dense_feats row, u1 -> bn4 -> leaky -> *score -> gf into LDS [k*33+c]
  int idx = p.nei[row];
  const float4* f4 = (const float4*)(p.dfeat + ((size_t)b*Nq + idx)*64);
  float fr[64];
  #pragma unroll
  for (int q = 0; q < 16; q++){
    float4 x = f4[q];
    fr[q*4+0]=x.x; fr[q*4+1]=x.y; fr[q*4+2]=x.z; fr[q*4+3]=x.w;
  }
  #pragma unroll
  for (int c = 0; c < 32; c++){
    float y = p.b_u1[c];
    #pragma unroll
    for (int j = 0; j < 64; j++) y += p.w_u1[c*64+j]*fr[j];
    float fx = lrelu((y - p.fs[G_BN4+c])*p.fs[G_BN4+32+c]);
    sp[k*33 + c] = fx*scr[c >> 3];
  }
  // ---- max over K of dense_feats; lane keeps quad q==k
  float sx0=0.f, sx1=0.f, sx2=0.f, sx3=0.f;
  #pragma unroll
  for (int q = 0; q < 16; q++){
    float m0=fr[q*4+0], m1=fr[q*4+1], m2=fr[q*4+2], m3=fr[q*4+3];
    m0=fmaxf(m0,__shfl_xor(m0,1,16)); m0=fmaxf(m0,__shfl_xor(m0,2,16)); m0=fmaxf(m0,__shfl_xor(m0,4,16)); m0=fmaxf(m0,__shfl_xor(m0,8,16));
    m1=fmaxf(m1,__shfl_xor(m1,1,16)); m1=fmaxf(m1,__shfl_xor(m1,2,16)); m1=fmaxf(m1,__shfl_xor(m1,4,16)); m1=fmaxf(m1,__shfl_xor(m1,8,16));
    m2=fmaxf(m2,__shfl_xor(m2,1,16)); m2=fmaxf(m2,__shfl_xor(m2,2,16)); m2=fmaxf(m2,__shfl_xor(m2,4,16)); m2=fmaxf(m2,__shfl_xor(m2,8,16));
    m3=fmaxf(m3,__shfl_xor(m3,1,16)); m3=fmaxf(m3,__shfl_xor(m3,2,16)); m3=fmaxf(m3,__shfl_xor(m3,4,16)); m3=fmaxf(m3,__shfl_xor(m3,8,16));
    if (q == k){ sx0=m0; sx1=m1; sx2=m2; sx3=m3; }
  }
  __syncthreads();   // gf visible

  // ---- pull transposed gf rows (channels c=k, c=k+16) into regs
  float ga[16], gb[16];
  #pragma unroll
  for (int kp = 0; kp < 16; kp++){
    ga[kp] = sp[kp*33 + k];
    gb[kp] = sp[kp*33 + k + 16];
  }
  __syncthreads();   // done reading gf; buffer reusable

  // ---- write wv -> LDS [kp*20+wi]
  {
    float4* d4p = (float4*)&sp[k*20];
    d4p[0] = make_float4(wv[0],wv[1],wv[2],wv[3]);
    d4p[1] = make_float4(wv[4],wv[5],wv[6],wv[7]);
    d4p[2] = make_float4(wv[8],wv[9],wv[10],wv[11]);
    d4p[3] = make_float4(wv[12],wv[13],wv[14],wv[15]);
  }
  __syncthreads();

  // ---- einsum: nf rows for channels c=k and c=k+16
  float nf0[16], nf1[16];
  #pragma unroll
  for (int wi = 0; wi < 16; wi++){ nf0[wi]=0.f; nf1[wi]=0.f; }
  #pragma unroll 4
  for (int kp = 0; kp < 16; kp++){
    const float4* wp = (const float4*)&sp[kp*20];
    float4 wa = wp[0], wb = wp[1], wc = wp[2], wd = wp[3];
    float wvv[16] = {wa.x,wa.y,wa.z,wa.w, wb.x,wb.y,wb.z,wb.w,
                     wc.x,wc.y,wc.z,wc.w, wd.x,wd.y,wd.z,wd.w};
    #pragma unroll
    for (int wi = 0; wi < 16; wi++){
      nf0[wi] += ga[kp]*wvv[wi];
      nf1[wi] += gb[kp]*wvv[wi];
    }
  }
  __syncthreads();   // done reading wv

  // ---- write nf(512) + smx(64) into LDS as a 576-wide row per point
  {
    float4* na = (float4*)&sp[k*16];
    na[0] = make_float4(nf0[0],nf0[1],nf0[2],nf0[3]);
    na[1] = make_float4(nf0[4],nf0[5],nf0[6],nf0[7]);
    na[2] = make_float4(nf0[8],nf0[9],nf0[10],nf0[11]);
    na[3] = make_float4(nf0[12],nf0[13],nf0[14],nf0[15]);
    float4* nb = (float4*)&sp[(k+16)*16];
    nb[0] = make_float4(nf1[0],nf1[1],nf1[2],nf1[3]);
    nb[1] = make_float4(nf1[4],nf1[5],nf1[6],nf1[7]);
    nb[2] = make_float4(nf1[8],nf1[9],nf1[10],nf1[11]);
    nb[3] = make_float4(nf1[12],nf1[13],nf1[14],nf1[15]);
    *(float4*)&sp[512 + k*4] = make_float4(sx0,sx1,sx2,sx3);
  }
  __syncthreads();   // nf|smx visible block-wide

  // ---- matvec: thread owns channel o; half-block owns 8 points. wc reads coalesced.
  int o   = t & 127;
  int ptg = t >> 7;
  float acc[8];
  #pragma unroll
  for (int i = 0; i < 8; i++) acc[i] = 0.f;
  #pragma unroll 2
  for (int d4 = 0; d4 < 128; d4++){
    const float* wr = p.wc + (size_t)(d4*4)*128 + o;
    float wa = wr[0], wb = wr[128], wcv = wr[256], wd = wr[384];
    #pragma unroll
    for (int i = 0; i < 8; i++){
      float4 av = *(const float4*)&sb[(ptg*8+i)*592 + d4*4];
      acc[i] += av.x*wa + av.y*wb + av.z*wcv + av.w*wd;
    }
  }
  float ac9[8];
  #pragma unroll
  for (int i = 0; i < 8; i++) ac9[i] = 0.f;
  #pragma unroll
  for (int d4 = 128; d4 < 144; d4++){
    const float* wr = p.wc + (size_t)(d4*4)*128 + o;
    float wa = wr[0], wb = wr[128], wcv = wr[256], wd = wr[384];
    #pragma unroll
    for (int i = 0; i < 8; i++){
      float4 av = *(const float4*)&sb[(ptg*8+i)*592 + d4*4];
      ac9[i] += av.x*wa + av.y*wb + av.z*wcv + av.w*wd;
    }
  }

  float bu2 = p.b_u2[o], bus = p.b_us[o];
  size_t obase = (size_t)(blockIdx.x*16)*128 + o;
  float s8=0.f, q8=0.f, s9=0.f, q9=0.f;
  #pragma unroll
  for (int i = 0; i < 8; i++){
    int pt = ptg*8 + i;
    float y8v = acc[i] + bu2;
    float y9v = ac9[i] + bus;
    p.y8[obase + (size_t)pt*128] = y8v;
    p.y9[obase + (size_t)pt*128] = y9v;
    s8 += y8v; q8 += y8v*y8v;
    s9 += y9v; q9 += y9v*y9v;
  }
  atomicAdd(&ls[o], s8);      atomicAdd(&ls[128+o], q8);
  atomicAdd(&ls[256+o], s9);  atomicAdd(&ls[384+o], q9);
  __syncthreads();
  atomicAdd(&p.ds[G_BN8+t], (double)ls[t]);
  atomicAdd(&p.ds[G_BN9+t], (double)ls[256+t]);
}

// ---------------------------------------------------------------- P5: out = leaky(bn8(y8)+bn9(y9))
__global__ __launch_bounds__(256) void k_out(P p){
  size_t i = ((size_t)blockIdx.x*256 + threadIdx.x)*4;
  int c = (int)(i & 127);
  float4 a  = *(const float4*)(p.y8 + i);
  float4 b4 = *(const float4*)(p.y9 + i);
  const float* m8 = p.fs + G_BN8;  const float* i8 = p.fs + G_BN8 + 128;
  const float* m9 = p.fs + G_BN9;  const float* i9 = p.fs + G_BN9 + 128;
  float r0 = lrelu((a.x - m8[c  ])*i8[c  ] + (b4.x - m9[c  ])*i9[c  ]);
  float r1 = lrelu((a.y - m8[c+1])*i8[c+1] + (b4.y - m9[c+1])*i9[c+1]);
  float r2 = lrelu((a.z - m8[c+2])*i8[c+2] + (b4.z - m9[c+2])*i9[c+2]);
  float r3 = lrelu((a.w - m8[c+3])*i8[c+3] + (b4.w - m9[c+3])*i9[c+3]);
  *(float4*)(p.out + i) = make_float4(r0,r1,r2,r3);
}

extern "C" void kernel_launch(void* const* d_in, const int* in_sizes, int n_in,
                              void* d_out, int out_size, void* d_ws, size_t ws_size,
                              hipStream_t stream){
  (void)in_sizes; (void)n_in; (void)out_size; (void)ws_size;
  P p;
  p.dxyz  = (const float*)d_in[0];
  p.sxyz  = (const float*)d_in[1];
  p.dfeat = (const float*)d_in[2];
  p.dnorm = (const float*)d_in[3];
  p.snorm = (const float*)d_in[4];
  p.w_mlp = (const float*)d_in[5];  p.b_mlp = (const float*)d_in[6];
  p.w_gu  = (const float*)d_in[7];  p.b_gu  = (const float*)d_in[8];
  p.w_gm0 = (const float*)d_in[9];  p.b_gm0 = (const float*)d_in[10];
  p.w_gm1 = (const float*)d_in[11]; p.b_gm1 = (const float*)d_in[12];
  p.w_u1  = (const float*)d_in[13]; p.b_u1  = (const float*)d_in[14];
  p.w_wn0 = (const float*)d_in[15]; p.b_wn0 = (const float*)d_in[16];
  p.w_wn1 = (const float*)d_in[17]; p.b_wn1 = (const float*)d_in[18];
  p.w_wn2 = (const float*)d_in[19]; p.b_wn2 = (const float*)d_in[20];
  p.w_u2  = (const float*)d_in[21]; p.b_u2  = (const float*)d_in[22];
  p.w_us  = (const float*)d_in[23]; p.b_us  = (const float*)d_in[24];
  p.nei   = (const int*)d_in[25];
  char* ws = (char*)d_ws;
  p.y8  = (float*)(ws + OFF_Y8);
  p.vi  = (float*)(ws + OFF_VI);
  p.y9  = (float*)d_out;            // y9 lives in d_out; k_out reads then overwrites
  p.ds  = (double*)(ws + OFF_DS);
  p.fs  = (float*)(ws + OFF_FS);
  p.wc  = (float*)(ws + OFF_WC);
  p.out = (float*)d_out;

  hipMemsetAsync(ws + OFF_DS, 0, 784*sizeof(double), stream);

  k_tr    <<< 288, 256, 0, stream>>>(p);
  k_vi    <<< 625, 256, 0, stream>>>(p);
  k_u1s   <<< 157, 256, 0, stream>>>(p);
  k_fin1  <<<   1, 128, 0, stream>>>(p);
  k_s2    <<< 625, 256, 0, stream>>>(p);
  k_fin2  <<<   1, 128, 0, stream>>>(p);
  k_s3    <<< 625, 256, 0, stream>>>(p);
  k_fin3  <<<   1, 128, 0, stream>>>(p);
  k_chain2<<<3125, 256, 0, stream>>>(p);
  k_fin4  <<<   1, 128, 0, stream>>>(p);
  k_out   <<<6250, 256, 0, stream>>>(p);
}

// Round 5
// 1200.919 us; speedup vs baseline: 6.4966x; 1.1608x over previous
//
#include <hip/hip_runtime.h>
#include <math.h>

// Problem constants
constexpr int Bq = 2;
constexpr int Nq = 100000;
constexpr int Mq = 25000;
constexpr int Kq = 16;
// rows (B,M,K) = 800000 ; points B*M = 50000 ; dense rows B*N = 200000

// ---- workspace layout (bytes) ----
// y4 (200000*32*4 = 25.6MB) aliases y8 (50000*128*4 = 25.6MB): y4 dead after k_fx, y8 written in k_chain2.
// fx (25.6MB) aliases vi (38.4MB): vi dead after k_s2 (its last reader), fx written after in k_fx.
constexpr size_t OFF_Y8  = 0;                    // 25,600,000  (also y4)
constexpr size_t OFF_VI  = 25600000;             // 38,400,000  (also fx)
constexpr size_t OFF_ZC  = 64000000;             // 800000*32*4 = 102,400,000
constexpr size_t OFF_W1P = 166400000;            // 800000*8*4  = 25,600,000
constexpr size_t OFF_DS  = 192000000;            // 784 doubles
constexpr size_t OFF_FS  = OFF_DS + 8192;        // 784 floats
constexpr size_t OFF_WC  = OFF_DS + 16384;       // 576*128*4 = 294912
// total ~192.4 MB ; y9 lives in d_out

// ---- stat-group offsets (shared for ds doubles and fs floats)
constexpr int G_BN1 = 0;    // C=32  n=800000
constexpr int G_BN5 = 64;   // C=8   n=800000
constexpr int G_BN4 = 80;   // C=32  n=200000
constexpr int G_BN2 = 144;  // C=32  n=800000
constexpr int G_BN6 = 208;  // C=8   n=800000
constexpr int G_BN3 = 224;  // C=8   n=800000
constexpr int G_BN7 = 240;  // C=16  n=800000
constexpr int G_BN8 = 272;  // C=128 n=50000
constexpr int G_BN9 = 528;  // C=128 n=50000

struct P {
  const float *dxyz,*sxyz,*dfeat,*dnorm,*snorm;
  const float *w_mlp,*b_mlp,*w_gu,*b_gu,*w_gm0,*b_gm0,*w_gm1,*b_gm1;
  const float *w_u1,*b_u1,*w_wn0,*b_wn0,*w_wn1,*b_wn1,*w_wn2,*b_wn2;
  const float *w_u2,*b_u2,*w_us,*b_us;
  const int* nei;
  float* vi; float* y8; float* y9; double* ds; float* fs;
  float* wc; float* zc; float* w1p; float* y4; float* fx; float* out;
};

__device__ __forceinline__ float lrelu(float x){ return x > 0.f ? x : 0.1f*x; }

__device__ __forceinline__ void load_vi(const P& p, int row, float v[12]){
  const float4* vp = (const float4*)(p.vi + (size_t)row*12);
  float4 a = vp[0], b = vp[1], c = vp[2];
  v[0]=a.x; v[1]=a.y; v[2]=a.z; v[3]=a.w;
  v[4]=b.x; v[5]=b.y; v[6]=b.z; v[7]=b.w;
  v[8]=c.x; v[9]=c.y; v[10]=c.z; v[11]=c.w;
}
// weights read from GLOBAL (uniform constant-offset -> SGPR s_loads, no VGPR pressure)
__device__ __forceinline__ void featpe(const P& p, const float v[12], float fp[32]){
  #pragma unroll
  for (int c = 0; c < 32; c++){
    float y = p.b_mlp[c];
    #pragma unroll
    for (int j = 0; j < 12; j++) y += p.w_mlp[c*12+j]*v[j];
    fp[c] = fmaxf((y - p.fs[G_BN1+c])*p.fs[G_BN1+32+c], 0.f);
  }
}
__device__ __forceinline__ void wchain0(const P& p, const float v[12], float w0[8]){
  #pragma unroll
  for (int c = 0; c < 8; c++){
    float y = p.b_wn0[c];
    #pragma unroll
    for (int j = 0; j < 12; j++) y += p.w_wn0[c*12+j]*v[j];
    w0[c] = fmaxf((y - p.fs[G_BN5+c])*p.fs[G_BN5+8+c], 0.f);
  }
}

// ---------------------------------------------------------------- k_tr: build wcat[576][128] = [u2^T ; us^T]
__global__ __launch_bounds__(256) void k_tr(P p){
  int i = blockIdx.x*256 + threadIdx.x;       // 288 blocks
  if (i < 576*128){
    int d = i >> 7, o = i & 127;
    p.wc[i] = (d < 512) ? p.w_u2[(size_t)o*512 + d] : p.w_us[(size_t)o*64 + (d-512)];
  }
}

// ---------------------------------------------------------------- P1: vi + bn1/bn5 moments (5 rows/thread)
__global__ __launch_bounds__(256) void k_vi(P p){
  __shared__ float ls[80];
  int t = threadIdx.x;
  if (t < 80) ls[t] = 0.f;
  __syncthreads();

  float a1[32], q1[32], a5[8], q5[8];
  #pragma unroll
  for (int c = 0; c < 32; c++){ a1[c]=0.f; q1[c]=0.f; }
  #pragma unroll
  for (int c = 0; c < 8; c++){ a5[c]=0.f; q5[c]=0.f; }

  int base = blockIdx.x*1280 + t;
  for (int r = 0; r < 5; r++){
    int row = base + r*256;
    int b   = row / (Mq*Kq);
    int rem = row - b*(Mq*Kq);
    int m   = rem >> 4;
    int bm  = b*Mq + m;
    int idx = p.nei[row];

    const float* gx = p.dxyz  + ((size_t)b*Nq + idx)*3;
    const float* gn = p.dnorm + ((size_t)b*Nq + idx)*3;
    const float* sx = p.sxyz  + (size_t)bm*3;
    const float* sn = p.snorm + (size_t)bm*3;

    float lx = gx[0]-sx[0], ly = gx[1]-sx[1], lz = gx[2]-sx[2];
    float gnx = gn[0], gny = gn[1], gnz = gn[2];
    float snx = sn[0], sny = sn[1], snz = sn[2];

    float rn = sqrtf(lx*lx + ly*ly + lz*lz);
    float rd = fmaxf(rn, 1e-12f);
    float rx = lx/rd, ry = ly/rd, rz = lz/rd;
    float proj = snx*rx + sny*ry + snz*rz;
    float vx = snx - proj*rx, vy = sny - proj*ry, vz = snz - proj*rz;
    float vn = sqrtf(vx*vx + vy*vy + vz*vz);
    float vd = fmaxf(vn, 1e-12f);
    vx /= vd; vy /= vd; vz /= vd;
    float wx = ry*vz - rz*vy, wy = rz*vx - rx*vz, wz = rx*vy - ry*vx;
    float wnn = sqrtf(wx*wx + wy*wy + wz*wz);
    float wd = fmaxf(wnn, 1e-12f);
    wx /= wd; wy /= wd; wz /= wd;
    float cx = gny*snz - gnz*sny, cy = gnz*snx - gnx*snz, cz = gnx*sny - gny*snx;

    float v[12];
    v[0] = gnx*snx + gny*sny + gnz*snz;
    v[1] = proj;
    v[2] = rx*gnx + ry*gny + rz*gnz;
    v[3] = lx*snx + ly*sny + lz*snz;
    v[4] = v[2];
    v[5] = gnx*vx + gny*vy + gnz*vz;
    v[6] = gnx*wx + gny*wy + gnz*wz;
    v[7] = lx*cx + ly*cy + lz*cz;
    v[8] = rn;
    v[9] = lx; v[10] = ly; v[11] = lz;

    float4* vo = (float4*)(p.vi + (size_t)row*12);
    vo[0] = make_float4(v[0],v[1],v[2],v[3]);
    vo[1] = make_float4(v[4],v[5],v[6],v[7]);
    vo[2] = make_float4(v[8],v[9],v[10],v[11]);

    #pragma unroll
    for (int c = 0; c < 32; c++){
      float y = p.b_mlp[c];
      #pragma unroll
      for (int j = 0; j < 12; j++) y += p.w_mlp[c*12 + j]*v[j];
      a1[c] += y; q1[c] += y*y;
    }
    #pragma unroll
    for (int c = 0; c < 8; c++){
      float y = p.b_wn0[c];
      #pragma unroll
      for (int j = 0; j < 12; j++) y += p.w_wn0[c*12 + j]*v[j];
      a5[c] += y; q5[c] += y*y;
    }
  }
  int lane = t & 63;
  #pragma unroll
  for (int i = 0; i < 32; i++){
    int c = (lane + i) & 31;
    atomicAdd(&ls[c], a1[c]); atomicAdd(&ls[32+c], q1[c]);
  }
  #pragma unroll
  for (int i = 0; i < 8; i++){
    int c = (lane + i) & 7;
    atomicAdd(&ls[64+c], a5[c]); atomicAdd(&ls[72+c], q5[c]);
  }
  __syncthreads();
  if (t < 32){
    atomicAdd(&p.ds[G_BN1+t], (double)ls[t]);
    atomicAdd(&p.ds[G_BN1+32+t], (double)ls[32+t]);
  } else if (t < 40){
    int c = t - 32;
    atomicAdd(&p.ds[G_BN5+c], (double)ls[64+c]);
    atomicAdd(&p.ds[G_BN5+8+c], (double)ls[72+c]);
  }
}

// ---------------------------------------------------------------- P1b: bn4 (u1) pre-act y4 + moments over B*N
__global__ __launch_bounds__(256) void k_u1s(P p){
  __shared__ float ls[64];
  int t = threadIdx.x;
  if (t < 64) ls[t] = 0.f;
  __syncthreads();
  float a4[32], q4[32];
  #pragma unroll
  for (int c = 0; c < 32; c++){ a4[c]=0.f; q4[c]=0.f; }
  int base = blockIdx.x*1280 + t;             // 157 blocks, guarded
  for (int r = 0; r < 5; r++){
    int row = base + r*256;
    if (row < Bq*Nq){
      const float4* f4 = (const float4*)(p.dfeat + (size_t)row*64);
      float fr[64];
      #pragma unroll
      for (int q = 0; q < 16; q++){
        float4 x = f4[q];
        fr[q*4+0]=x.x; fr[q*4+1]=x.y; fr[q*4+2]=x.z; fr[q*4+3]=x.w;
      }
      float zb[4];
      #pragma unroll
      for (int c = 0; c < 32; c++){
        float y = p.b_u1[c];
        #pragma unroll
        for (int j = 0; j < 64; j++) y += p.w_u1[c*64 + j]*fr[j];
        a4[c] += y; q4[c] += y*y;
        zb[c & 3] = y;
        if ((c & 3) == 3)
          *(float4*)(p.y4 + (size_t)row*32 + (c-3)) = make_float4(zb[0],zb[1],zb[2],zb[3]);
      }
    }
  }
  int lane = t & 63;
  #pragma unroll
  for (int i = 0; i < 32; i++){
    int c = (lane + i) & 31;
    atomicAdd(&ls[c], a4[c]); atomicAdd(&ls[32+c], q4[c]);
  }
  __syncthreads();
  if (t < 32){
    atomicAdd(&p.ds[G_BN4+t], (double)ls[t]);
    atomicAdd(&p.ds[G_BN4+32+t], (double)ls[32+t]);
  }
}

// ---------------------------------------------------------------- stat finalize
__device__ __forceinline__ void fin_group(const double* ds, float* fs, int off, int C, double n){
  for (int c = threadIdx.x; c < C; c += blockDim.x){
    double s = ds[off+c], q = ds[off+C+c];
    double mu = s/n;
    double va = q/n - mu*mu;
    if (va < 0.0) va = 0.0;
    fs[off+c]   = (float)mu;
    fs[off+C+c] = 1.f/sqrtf((float)va + 1e-5f);
  }
}
__global__ void k_fin1(P p){ fin_group(p.ds,p.fs,G_BN1,32,800000.0); fin_group(p.ds,p.fs,G_BN5,8,800000.0); fin_group(p.ds,p.fs,G_BN4,32,200000.0); }
__global__ void k_fin2(P p){ fin_group(p.ds,p.fs,G_BN2,32,800000.0); fin_group(p.ds,p.fs,G_BN6,8,800000.0); }
__global__ void k_fin3(P p){ fin_group(p.ds,p.fs,G_BN3,8,800000.0);  fin_group(p.ds,p.fs,G_BN7,16,800000.0); }
__global__ void k_fin4(P p){ fin_group(p.ds,p.fs,G_BN8,128,50000.0); fin_group(p.ds,p.fs,G_BN9,128,50000.0); }

// ---------------------------------------------------------------- P2: point-aligned; bn2/bn6 moments,
// store z = y2 - max_K(y2) (the bn2-invariant guidance-minus-key) and w1pre.
__global__ __launch_bounds__(256) void k_s2(P p){
  __shared__ float ls[80];
  int t = threadIdx.x;
  if (t < 80) ls[t] = 0.f;
  __syncthreads();
  int lane = t & 63;
  int k  = lane & 15;
  int pl = (t >> 6)*4 + (lane >> 4);
  float a2[32], q2[32], a6[8], q6[8];
  #pragma unroll
  for (int c = 0; c < 32; c++){ a2[c]=0.f; q2[c]=0.f; }
  #pragma unroll
  for (int c = 0; c < 8; c++){ a6[c]=0.f; q6[c]=0.f; }

  for (int it = 0; it < 5; it++){
    int pg = blockIdx.x*80 + it*16 + pl;      // 625 blocks cover 50000 pts
    int row = pg*16 + k;
    float v[12]; load_vi(p, row, v);
    float fp[32]; featpe(p, v, fp);
    float zb[4];
    #pragma unroll
    for (int c = 0; c < 32; c++){
      float y = p.b_gu[c];
      #pragma unroll
      for (int j = 0; j < 32; j++) y += p.w_gu[c*32+j]*fp[j];
      a2[c] += y; q2[c] += y*y;
      float mx = y;
      mx = fmaxf(mx, __shfl_xor(mx, 1, 16));
      mx = fmaxf(mx, __shfl_xor(mx, 2, 16));
      mx = fmaxf(mx, __shfl_xor(mx, 4, 16));
      mx = fmaxf(mx, __shfl_xor(mx, 8, 16));
      zb[c & 3] = y - mx;
      if ((c & 3) == 3)
        *(float4*)(p.zc + (size_t)row*32 + (c-3)) = make_float4(zb[0],zb[1],zb[2],zb[3]);
    }
    float w0[8]; wchain0(p, v, w0);
    float wb[8];
    #pragma unroll
    for (int c = 0; c < 8; c++){
      float y = p.b_wn1[c];
      #pragma unroll
      for (int j = 0; j < 8; j++) y += p.w_wn1[c*8+j]*w0[j];
      a6[c] += y; q6[c] += y*y;
      wb[c] = y;
    }
    float4* wp = (float4*)(p.w1p + (size_t)row*8);
    wp[0] = make_float4(wb[0],wb[1],wb[2],wb[3]);
    wp[1] = make_float4(wb[4],wb[5],wb[6],wb[7]);
  }
  #pragma unroll
  for (int i = 0; i < 32; i++){
    int c = (lane + i) & 31;
    atomicAdd(&ls[c], a2[c]); atomicAdd(&ls[32+c], q2[c]);
  }
  #pragma unroll
  for (int i = 0; i < 8; i++){
    int c = (lane + i) & 7;
    atomicAdd(&ls[64+c], a6[c]); atomicAdd(&ls[72+c], q6[c]);
  }
  __syncthreads();
  if (t < 32){
    atomicAdd(&p.ds[G_BN2+t], (double)ls[t]);
    atomicAdd(&p.ds[G_BN2+32+t], (double)ls[32+t]);
  } else if (t < 40){
    int c = t - 32;
    atomicAdd(&p.ds[G_BN6+c], (double)ls[64+c]);
    atomicAdd(&p.ds[G_BN6+8+c], (double)ls[72+c]);
  }
}

// ---------------------------------------------------------------- k_fx: feats_x = lrelu(bn4(y4)) on dense rows
__global__ __launch_bounds__(256) void k_fx(P p){
  int gid = blockIdx.x*256 + threadIdx.x;     // 6250 blocks: 1.6M float4
  size_t i = (size_t)gid*4;
  int c = (int)(i & 31);
  float4 y = *(const float4*)(p.y4 + i);
  float4 r;
  r.x = lrelu((y.x - p.fs[G_BN4+c  ])*p.fs[G_BN4+32+c  ]);
  r.y = lrelu((y.y - p.fs[G_BN4+c+1])*p.fs[G_BN4+32+c+1]);
  r.z = lrelu((y.z - p.fs[G_BN4+c+2])*p.fs[G_BN4+32+c+2]);
  r.w = lrelu((y.w - p.fs[G_BN4+c+3])*p.fs[G_BN4+32+c+3]);
  *(float4*)(p.fx + i) = r;
}

// ---------------------------------------------------------------- P3: bn3/bn7 moments from stored z / w1p (flat)
__global__ __launch_bounds__(256) void k_s3(P p){
  __shared__ float ls[48];
  int t = threadIdx.x;
  if (t < 48) ls[t] = 0.f;
  __syncthreads();
  float a3[8], q3[8], a7[16], q7[16];
  #pragma unroll
  for (int c = 0; c < 8; c++){ a3[c]=0.f; q3[c]=0.f; }
  #pragma unroll
  for (int c = 0; c < 16; c++){ a7[c]=0.f; q7[c]=0.f; }

  int base = blockIdx.x*1280 + t;
  for (int r = 0; r < 5; r++){
    int row = base + r*256;
    // g = z * inv2
    float g[32];
    const float4* zp = (const float4*)(p.zc + (size_t)row*32);
    #pragma unroll
    for (int q = 0; q < 8; q++){
      float4 z = zp[q];
      g[q*4+0] = z.x*p.fs[G_BN2+32+q*4+0];
      g[q*4+1] = z.y*p.fs[G_BN2+32+q*4+1];
      g[q*4+2] = z.z*p.fs[G_BN2+32+q*4+2];
      g[q*4+3] = z.w*p.fs[G_BN2+32+q*4+3];
    }
    #pragma unroll
    for (int c = 0; c < 8; c++){
      float y = p.b_gm0[c];
      #pragma unroll
      for (int j = 0; j < 32; j++) y += p.w_gm0[c*32+j]*g[j];
      a3[c] += y; q3[c] += y*y;
    }
    const float4* wp = (const float4*)(p.w1p + (size_t)row*8);
    float4 wa = wp[0], wbv = wp[1];
    float w1[8] = {wa.x,wa.y,wa.z,wa.w, wbv.x,wbv.y,wbv.z,wbv.w};
    #pragma unroll
    for (int c = 0; c < 8; c++)
      w1[c] = fmaxf((w1[c] - p.fs[G_BN6+c])*p.fs[G_BN6+8+c], 0.f);
    #pragma unroll
    for (int c = 0; c < 16; c++){
      float y = p.b_wn2[c];
      #pragma unroll
      for (int j = 0; j < 8; j++) y += p.w_wn2[c*8+j]*w1[j];
      a7[c] += y; q7[c] += y*y;
    }
  }
  int lane = t & 63;
  #pragma unroll
  for (int i = 0; i < 8; i++){
    int c = (lane + i) & 7;
    atomicAdd(&ls[c], a3[c]); atomicAdd(&ls[8+c], q3[c]);
  }
  #pragma unroll
  for (int i = 0; i < 16; i++){
    int c = (lane + i) & 15;
    atomicAdd(&ls[16+c], a7[c]); atomicAdd(&ls[32+c], q7[c]);
  }
  __syncthreads();
  if (t < 8){
    atomicAdd(&p.ds[G_BN3+t], (double)ls[t]);
    atomicAdd(&p.ds[G_BN3+8+t], (double)ls[8+t]);
  } else if (t < 24){
    int c = t - 8;
    atomicAdd(&p.ds[G_BN7+c], (double)ls[16+c]);
    atomicAdd(&p.ds[G_BN7+16+c], (double)ls[32+c]);
  }
}

// ---------------------------------------------------------------- P4: fused lean chain + einsum + 576x128 matvec
__global__ __launch_bounds__(256) void k_chain2(P p){
  __shared__ __align__(16) float sb[16*592];
  __shared__ float ls[512];
  int t = threadIdx.x;
  ls[t] = 0.f; ls[t+256] = 0.f;

  int lane = t & 63;
  int k  = lane & 15;
  int pl = (t >> 6)*4 + (lane >> 4);
  int pg = blockIdx.x*16 + pl;
  int b  = pg / Mq;
  int row = pg*16 + k;
  float* sp = &sb[pl*592];

  // ---- g = z*inv2 ; sc = relu(bn3(gm0.g)) ; scr = sigmoid(gm1.sc)
  float g[32];
  {
    const float4* zp = (const float4*)(p.zc + (size_t)row*32);
    #pragma unroll
    for (int q = 0; q < 8; q++){
      float4 z = zp[q];
      g[q*4+0] = z.x*p.fs[G_BN2+32+q*4+0];
      g[q*4+1] = z.y*p.fs[G_BN2+32+q*4+1];
      g[q*4+2] = z.z*p.fs[G_BN2+32+q*4+2];
      g[q*4+3] = z.w*p.fs[G_BN2+32+q*4+3];
    }
  }
  float sc[8];
  #pragma unroll
  for (int c = 0; c < 8; c++){
    float y = p.b_gm0[c];
    #pragma unroll
    for (int j = 0; j < 32; j++) y += p.w_gm0[c*32+j]*g[j];
    sc[c] = fmaxf((y - p.fs[G_BN3+c])*p.fs[G_BN3+8+c], 0.f);
  }
  float scr[4];
  #pragma unroll
  for (int h = 0; h < 4; h++){
    float y = p.b_gm1[h];
    #pragma unroll
    for (int j = 0; j < 8; j++) y += p.w_gm1[h*8+j]*sc[j];
    scr[h] = 1.f/(1.f + expf(-y));
  }
  // ---- wv = relu(bn7(wn2.relu(bn6(w1p))))
  float wv[16];
  {
    const float4* wp = (const float4*)(p.w1p + (size_t)row*8);
    float4 wa = wp[0], wbv = wp[1];
    float w1[8] = {wa.x,wa.y,wa.z,wa.w, wbv.x,wbv.y,wbv.z,wbv.w};
    #pragma unroll
    for (int c = 0; c < 8; c++)
      w1[c] = fmaxf((w1[c] - p.fs[G_BN6+c])*p.fs[G_BN6+8+c], 0.f);
    #pragma unroll
    for (int c = 0; c < 16; c++){
      float y = p.b_wn2[c];
      #pragma unroll
      for (int j = 0; j < 8; j++) y += p.w_wn2[c*8+j]*w1[j];
      wv[c] = fmaxf((y - p.fs[G_BN7+c])*p.fs[G_BN7+16+c], 0.f);
    }
  }

  // ---- gather feats_x (32ch) -> gf = fx*scr into LDS [k*33+c]
  int idx = p.nei[row];
  {
    const float4* x4 = (const float4*)(p.fx + ((size_t)b*Nq + idx)*32);
    #pragma unroll
    for (int q = 0; q < 8; q++){
      float4 x = x4[q];
      int c = q*4;
      sp[k*33 + c  ] = x.x*scr[c>>3];
      sp[k*33 + c+1] = x.y*scr[c>>3];
      sp[k*33 + c+2] = x.z*scr[c>>3];
      sp[k*33 + c+3] = x.w*scr[c>>3];
    }
  }
  // ---- gather dense_feats (64ch) for max over K; lane keeps quad q==k
  float sx0=0.f, sx1=0.f, sx2=0.f, sx3=0.f;
  {
    const float4* f4 = (const float4*)(p.dfeat + ((size_t)b*Nq + idx)*64);
    float fr[64];
    #pragma unroll
    for (int q = 0; q < 16; q++){
      float4 x = f4[q];
      fr[q*4+0]=x.x; fr[q*4+1]=x.y; fr[q*4+2]=x.z; fr[q*4+3]=x.w;
    }
    #pragma unroll
    for (int q = 0; q < 16; q++){
      float m0=fr[q*4+0], m1=fr[q*4+1], m2=fr[q*4+2], m3=fr[q*4+3];
      m0=fmaxf(m0,__shfl_xor(m0,1,16)); m0=fmaxf(m0,__shfl_xor(m0,2,16)); m0=fmaxf(m0,__shfl_xor(m0,4,16)); m0=fmaxf(m0,__shfl_xor(m0,8,16));
      m1=fmaxf(m1,__shfl_xor(m1,1,16)); m1=fmaxf(m1,__shfl_xor(m1,2,16)); m1=fmaxf(m1,__shfl_xor(m1,4,16)); m1=fmaxf(m1,__shfl_xor(m1,8,16));
      m2=fmaxf(m2,__shfl_xor(m2,1,16)); m2=fmaxf(m2,__shfl_xor(m2,2,16)); m2=fmaxf(m2,__shfl_xor(m2,4,16)); m2=fmaxf(m2,__shfl_xor(m2,8,16));
      m3=fmaxf(m3,__shfl_xor(m3,1,16)); m3=fmaxf(m3,__shfl_xor(m3,2,16)); m3=fmaxf(m3,__shfl_xor(m3,4,16)); m3=fmaxf(m3,__shfl_xor(m3,8,16));
      if (q == k){ sx0=m0; sx1=m1; sx2=m2; sx3=m3; }
    }
  }
  __syncthreads();   // gf visible

  // ---- pull transposed gf rows (channels c=k, c=k+16) into regs
  float ga[16], gb[16];
  #pragma unroll
  for (int kp = 0; kp < 16; kp++){
    ga[kp] = sp[kp*33 + k];
    gb[kp] = sp[kp*33 + k + 16];
  }
  __syncthreads();   // done reading gf; buffer reusable

  // ---- write wv -> LDS [kp*20+wi]
  {
    float4* d4p = (float4*)&sp[k*20];
    d4p[0] = make_float4(wv[0],wv[1],wv[2],wv[3]);
    d4p[1] = make_float4(wv[4],wv[5],wv[6],wv[7]);
    d4p[2] = make_float4(wv[8],wv[9],wv[10],wv[11]);
    d4p[3] = make_float4(wv[12],wv[13],wv[14],wv[15]);
  }
  __syncthreads();

  // ---- einsum: nf rows for channels c=k and c=k+16
  float nf0[16], nf1[16];
  #pragma unroll
  for (int wi = 0; wi < 16; wi++){ nf0[wi]=0.f; nf1[wi]=0.f; }
  #pragma unroll 4
  for (int kp = 0; kp < 16; kp++){
    const float4* wp = (const float4*)&sp[kp*20];
    float4 wa = wp[0], wb = wp[1], wc = wp[2], wd = wp[3];
    float wvv[16] = {wa.x,wa.y,wa.z,wa.w, wb.x,wb.y,wb.z,wb.w,
                     wc.x,wc.y,wc.z,wc.w, wd.x,wd.y,wd.z,wd.w};
    #pragma unroll
    for (int wi = 0; wi < 16; wi++){
      nf0[wi] += ga[kp]*wvv[wi];
      nf1[wi] += gb[kp]*wvv[wi];
    }
  }
  __syncthreads();   // done reading wv

  // ---- write nf(512) + smx(64) into LDS as a 576-wide row per point
  {
    float4* na = (float4*)&sp[k*16];
    na[0] = make_float4(nf0[0],nf0[1],nf0[2],nf0[3]);
    na[1] = make_float4(nf0[4],nf0[5],nf0[6],nf0[7]);
    na[2] = make_float4(nf0[8],nf0[9],nf0[10],nf0[11]);
    na[3] = make_float4(nf0[12],nf0[13],nf0[14],nf0[15]);
    float4* nb = (float4*)&sp[(k+16)*16];
    nb[0] = make_float4(nf1[0],nf1[1],nf1[2],nf1[3]);
    nb[1] = make_float4(nf1[4],nf1[5],nf1[6],nf1[7]);
    nb[2] = make_float4(nf1[8],nf1[9],nf1[10],nf1[11]);
    nb[3] = make_float4(nf1[12],nf1[13],nf1[14],nf1[15]);
    *(float4*)&sp[512 + k*4] = make_float4(sx0,sx1,sx2,sx3);
  }
  __syncthreads();   // nf|smx visible block-wide

  // ---- matvec: thread owns channel o; half-block owns 8 points. wc reads coalesced.
  int o   = t & 127;
  int ptg = t >> 7;
  float acc[8];
  #pragma unroll
  for (int i = 0; i < 8; i++) acc[i] = 0.f;
  #pragma unroll 2
  for (int d4 = 0; d4 < 128; d4++){
    const float* wr = p.wc + (size_t)(d4*4)*128 + o;
    float wa = wr[0], wb = wr[128], wcv = wr[256], wd = wr[384];
    #pragma unroll
    for (int i = 0; i < 8; i++){
      float4 av = *(const float4*)&sb[(ptg*8+i)*592 + d4*4];
      acc[i] += av.x*wa + av.y*wb + av.z*wcv + av.w*wd;
    }
  }
  float ac9[8];
  #pragma unroll
  for (int i = 0; i < 8; i++) ac9[i] = 0.f;
  #pragma unroll
  for (int d4 = 128; d4 < 144; d4++){
    const float* wr = p.wc + (size_t)(d4*4)*128 + o;
    float wa = wr[0], wb = wr[128], wcv = wr[256], wd = wr[384];
    #pragma unroll
    for (int i = 0; i < 8; i++){
      float4 av = *(const float4*)&sb[(ptg*8+i)*592 + d4*4];
      ac9[i] += av.x*wa + av.y*wb + av.z*wcv + av.w*wd;
    }
  }

  float bu2 = p.b_u2[o], bus = p.b_us[o];
  size_t obase = (size_t)(blockIdx.x*16)*128 + o;
  float s8=0.f, q8=0.f, s9=0.f, q9=0.f;
  #pragma unroll
  for (int i = 0; i < 8; i++){
    int pt = ptg*8 + i;
    float y8v = acc[i] + bu2;
    float y9v = ac9[i] + bus;
    p.y8[obase + (size_t)pt*128] = y8v;
    p.y9[obase + (size_t)pt*128] = y9v;
    s8 += y8v; q8 += y8v*y8v;
    s9 += y9v; q9 += y9v*y9v;
  }
  atomicAdd(&ls[o], s8);      atomicAdd(&ls[128+o], q8);
  atomicAdd(&ls[256+o], s9);  atomicAdd(&ls[384+o], q9);
  __syncthreads();
  atomicAdd(&p.ds[G_BN8+t], (double)ls[t]);
  atomicAdd(&p.ds[G_BN9+t], (double)ls[256+t]);
}

// ---------------------------------------------------------------- P5: out = leaky(bn8(y8)+bn9(y9))
__global__ __launch_bounds__(256) void k_out(P p){
  size_t i = ((size_t)blockIdx.x*256 + threadIdx.x)*4;
  int c = (int)(i & 127);
  float4 a  = *(const float4*)(p.y8 + i);
  float4 b4 = *(const float4*)(p.y9 + i);
  const float* m8 = p.fs + G_BN8;  const float* i8 = p.fs + G_BN8 + 128;
  const float* m9 = p.fs + G_BN9;  const float* i9 = p.fs + G_BN9 + 128;
  float r0 = lrelu((a.x - m8[c  ])*i8[c  ] + (b4.x - m9[c  ])*i9[c  ]);
  float r1 = lrelu((a.y - m8[c+1])*i8[c+1] + (b4.y - m9[c+1])*i9[c+1]);
  float r2 = lrelu((a.z - m8[c+2])*i8[c+2] + (b4.z - m9[c+2])*i9[c+2]);
  float r3 = lrelu((a.w - m8[c+3])*i8[c+3] + (b4.w - m9[c+3])*i9[c+3]);
  *(float4*)(p.out + i) = make_float4(r0,r1,r2,r3);
}

extern "C" void kernel_launch(void* const* d_in, const int* in_sizes, int n_in,
                              void* d_out, int out_size, void* d_ws, size_t ws_size,
                              hipStream_t stream){
  (void)in_sizes; (void)n_in; (void)out_size; (void)ws_size;
  P p;
  p.dxyz  = (const float*)d_in[0];
  p.sxyz  = (const float*)d_in[1];
  p.dfeat = (const float*)d_in[2];
  p.dnorm = (const float*)d_in[3];
  p.snorm = (const float*)d_in[4];
  p.w_mlp = (const float*)d_in[5];  p.b_mlp = (const float*)d_in[6];
  p.w_gu  = (const float*)d_in[7];  p.b_gu  = (const float*)d_in[8];
  p.w_gm0 = (const float*)d_in[9];  p.b_gm0 = (const float*)d_in[10];
  p.w_gm1 = (const float*)d_in[11]; p.b_gm1 = (const float*)d_in[12];
  p.w_u1  = (const float*)d_in[13]; p.b_u1  = (const float*)d_in[14];
  p.w_wn0 = (const float*)d_in[15]; p.b_wn0 = (const float*)d_in[16];
  p.w_wn1 = (const float*)d_in[17]; p.b_wn1 = (const float*)d_in[18];
  p.w_wn2 = (const float*)d_in[19]; p.b_wn2 = (const float*)d_in[20];
  p.w_u2  = (const float*)d_in[21]; p.b_u2  = (const float*)d_in[22];
  p.w_us  = (const float*)d_in[23]; p.b_us  = (const float*)d_in[24];
  p.nei   = (const int*)d_in[25];
  char* ws = (char*)d_ws;
  p.y8  = (float*)(ws + OFF_Y8);
  p.y4  = (float*)(ws + OFF_Y8);    // alias: y4 dead before y8 written
  p.vi  = (float*)(ws + OFF_VI);
  p.fx  = (float*)(ws + OFF_VI);    // alias: fx written after vi's last read
  p.zc  = (float*)(ws + OFF_ZC);
  p.w1p = (float*)(ws + OFF_W1P);
  p.y9  = (float*)d_out;            // y9 lives in d_out; k_out reads then overwrites
  p.ds  = (double*)(ws + OFF_DS);
  p.fs  = (float*)(ws + OFF_FS);
  p.wc  = (float*)(ws + OFF_WC);
  p.out = (float*)d_out;

  hipMemsetAsync(ws + OFF_DS, 0, 784*sizeof(double), stream);

  k_tr    <<< 288, 256, 0, stream>>>(p);
  k_vi    <<< 625, 256, 0, stream>>>(p);
  k_u1s   <<< 157, 256, 0, stream>>>(p);
  k_fin1  <<<   1, 128, 0, stream>>>(p);
  k_s2    <<< 625, 256, 0, stream>>>(p);   // reads vi (last reader), writes zc/w1p
  k_fx    <<<6250, 256, 0, stream>>>(p);   // y4 -> fx (into old vi region)
  k_fin2  <<<   1, 128, 0, stream>>>(p);
  k_s3    <<< 625, 256, 0, stream>>>(p);   // reads zc/w1p only
  k_fin3  <<<   1, 128, 0, stream>>>(p);
  k_chain2<<<3125, 256, 0, stream>>>(p);   // reads zc/w1p/fx/dfeat, writes y8/y9
  k_fin4  <<<   1, 128, 0, stream>>>(p);
  k_out   <<<6250, 256, 0, stream>>>(p);
}